// Round 2
// baseline (1095.465 us; speedup 1.0000x reference)
//
#include <hip/hip_runtime.h>

typedef _Float16 half_t;
typedef _Float16 h8 __attribute__((ext_vector_type(8)));
typedef _Float16 h2 __attribute__((ext_vector_type(2)));
typedef float f4 __attribute__((ext_vector_type(4)));
typedef unsigned int uint32;
typedef unsigned int u2v __attribute__((ext_vector_type(2)));

#define SHIFT16 2.772588722239781f    // log(16), fast path
#define SHIFT8  2.0794415416798357f   // log(8), fallback path
// ws float offsets:  X[64][128] | Q[64][128] | Lf[64] | Lb[64] | pad | eo16
#define WX 0
#define WQ 8192
#define WLF 16384
#define WLB 16448
#define EO_BYTE_OFF 66560u
#define FAST_WS_BYTES (EO_BYTE_OFF + 67108864u)   // eo = 4cg*4096t*64l*64B

typedef const __attribute__((address_space(1))) void gas_void;
typedef __attribute__((address_space(3))) void las_void;
typedef __attribute__((address_space(3))) uint32 las_u32;

// async global->LDS, 16B/lane, no dest VGPRs (nothing for regalloc to sink)
#define GLOAD16(gp, lp) \
    __builtin_amdgcn_global_load_lds((gas_void*)(gp), (las_void*)(lp), 16, 0, 0)

#define WAIT_VM(n)   asm volatile("s_waitcnt vmcnt(" #n ")" ::: "memory")
#define WAIT_LGKM(n) asm volatile("s_waitcnt lgkmcnt(" #n ")" ::: "memory")

// inline-asm ds_read: invisible to compiler alias analysis, so no auto
// vmcnt(0) drains against the in-flight LDS-DMA; we count waits ourselves.
#define DSR128(dst, addr, imm) \
    asm volatile("ds_read_b128 %0, %1 offset:%2" : "=v"(dst) : "v"(addr), "n"(imm))

__device__ __forceinline__ h2 pkrtz(float a, float b) {
    return __builtin_bit_cast(h2, __builtin_amdgcn_cvt_pkrtz(a, b));
}

// (a,b) <- ([a.lanes0-31 | b.lanes0-31], [a.lanes32-63 | b.lanes32-63])
__device__ __forceinline__ void swap32(uint32& a, uint32& b) {
#if __has_builtin(__builtin_amdgcn_permlane32_swap)
    u2v r = __builtin_amdgcn_permlane32_swap(a, b, false, false);
    a = r.x; b = r.y;
#else
    const uint32 pa = (uint32)__shfl_xor((int)a, 32);
    const uint32 pb = (uint32)__shfl_xor((int)b, 32);
    const bool hi = (threadIdx.x & 32) != 0;
    const uint32 na = hi ? pb : a;
    const uint32 nb = hi ? b : pa;
    a = na; b = nb;
#endif
}
// per 32-lane half: (a,b) <- ([a0-15|b0-15|a32-47|b32-47], [a16-31|b16-31|a48-63|b48-63])
__device__ __forceinline__ void swap16(uint32& a, uint32& b) {
#if __has_builtin(__builtin_amdgcn_permlane16_swap)
    u2v r = __builtin_amdgcn_permlane16_swap(a, b, false, false);
    a = r.x; b = r.y;
#else
    const uint32 sa = (uint32)__builtin_amdgcn_ds_swizzle((int)a, 0x401F);
    const uint32 sb = (uint32)__builtin_amdgcn_ds_swizzle((int)b, 0x401F);
    const bool m = (threadIdx.x & 16) != 0;
    const uint32 na = m ? sb : a;
    const uint32 nb = m ? b : sa;
    a = na; b = nb;
#endif
}

// pure-VALU wave max over lane bits 4 and 5 (no lgkm ops in the hot loop)
__device__ __forceinline__ float wavemax_hi(float M) {
    uint32 ma = __builtin_bit_cast(uint32, M), mb = ma;
    swap16(ma, mb);
    M = fmaxf(__builtin_bit_cast(float, ma), __builtin_bit_cast(float, mb));
    ma = __builtin_bit_cast(uint32, M); mb = ma;
    swap32(ma, mb);
    return fmaxf(__builtin_bit_cast(float, ma), __builtin_bit_cast(float, mb));
}

// ============================ FAST PATH =====================================

// eo16[cg][t][g 0..3][lane l]: fp16 exp(obs-SHIFT16) pairs in MFMA D-layout
// order, tile-transposed so that consumer ds_read_b128 #j at byte j*1024+l*16
// is contiguous (tile dword j*256+4l holds old er[j] dword of lane l).
__global__ __launch_bounds__(256)
void eo_prep(const float* __restrict__ obs, uint32* __restrict__ eo)
{
    __shared__ float sb[64 * 130];       // 64 rows (n,tl) x 128 floats, padded
    const int tid = threadIdx.x;
    const int cg = blockIdx.x >> 10;     // 4 chain-groups
    const int tb = blockIdx.x & 1023;    // 1024 blocks of 4 timesteps

    #pragma unroll
    for (int i = 0; i < 8; ++i) {        // load 64x128 floats, coalesced
        const int idx = i * 256 + tid;   // 2048 float4s
        const int row = idx >> 5, c4 = idx & 31;
        const int n = row >> 2, tl = row & 3;
        const float4 v = *(const float4*)
            &obs[((size_t)(cg * 16 + n) * 4096 + (tb * 4 + tl)) * 128 + c4 * 4];
        *(float4*)&sb[row * 130 + c4 * 4] = v;
    }
    __syncthreads();

    const int gg = tid >> 6;             // dword-group 0..3
    const int l  = tid & 63;             // output lane 0..63
    const int q = l >> 4, nn = l & 15;
    #pragma unroll
    for (int tl = 0; tl < 4; ++tl) {
        uint4 o;
        uint32* po = &o.x;
        #pragma unroll
        for (int j = 0; j < 4; ++j) {
            const int hd = gg * 4 + j;
            const int mt = hd >> 1, rr = (hd & 1) * 2;
            const int s = mt * 16 + q * 4 + rr;
            const float* p = &sb[(nn * 4 + tl) * 130 + s];
            po[j] = __builtin_bit_cast(uint32,
                      pkrtz(__expf(p[0] - SHIFT16), __expf(p[1] - SHIFT16)));
        }
        *(uint4*)&eo[((size_t)(cg * 4096 + tb * 4 + tl) << 10) + (gg << 8) + (l << 2)] = o;
    }
}

#define TE(N) (FW ? (N) : (4095 - (N)))

template <bool FW, int NIT, int ST>
__device__ __forceinline__ void cstep(int it, f4 (&D)[8], const uint32* ep,
                                      const h8 (&Af)[8][4], float& Lacc, float& rs)
{
    const f4 Z = {0.f, 0.f, 0.f, 0.f};

    if (ST == 0) {                       // apply pending renorm (fp32, exact)
        #pragma unroll
        for (int mt = 0; mt < 8; ++mt) D[mt] = D[mt] * rs;
    }
    if (ST == 3) {
        if (it != NIT - 1) {             // measure; pure VALU (permlane max)
            f4 m01 = __builtin_elementwise_max(D[0], D[1]);
            f4 m23 = __builtin_elementwise_max(D[2], D[3]);
            f4 m45 = __builtin_elementwise_max(D[4], D[5]);
            f4 m67 = __builtin_elementwise_max(D[6], D[7]);
            f4 ma = __builtin_elementwise_max(
                        __builtin_elementwise_max(m01, m23),
                        __builtin_elementwise_max(m45, m67));
            float M = fmaxf(fmaxf(ma.x, ma.y), fmaxf(ma.z, ma.w));
            M = wavemax_hi(M);
            Lacc += __logf(M);
            rs = __builtin_amdgcn_rcpf(M);
        }
    }

    // pack W = fp16(D) * eo  (register-resident)
    uint32 Wx[8], Wy[8];
    #pragma unroll
    for (int mt = 0; mt < 8; ++mt) {
        h2 w0 = pkrtz(D[mt].x, D[mt].y) * __builtin_bit_cast(h2, ep[2 * mt]);
        h2 w1 = pkrtz(D[mt].z, D[mt].w) * __builtin_bit_cast(h2, ep[2 * mt + 1]);
        Wx[mt] = __builtin_bit_cast(uint32, w0);
        Wy[mt] = __builtin_bit_cast(uint32, w1);
    }

    // cross-lane permute D-layout -> B-fragment layout (no LDS)
    h8 Bf[4];
    #pragma unroll
    for (int kc = 0; kc < 4; ++kc) {
        uint32 x0 = Wx[2 * kc], x1 = Wx[2 * kc + 1];
        uint32 y0 = Wy[2 * kc], y1 = Wy[2 * kc + 1];
        swap32(x0, x1); swap16(x0, x1);   // x0=d0, x1=d2
        swap32(y0, y1); swap16(y0, y1);   // y0=d1, y1=d3
        uint4 bv; bv.x = x0; bv.y = y0; bv.z = x1; bv.w = y1;
        Bf[kc] = __builtin_bit_cast(h8, bv);
    }

    // 32 MFMAs: 8 independent mt chains of depth 4
    #pragma unroll
    for (int mt = 0; mt < 8; ++mt) {
        f4 acc = Z;
        acc = __builtin_amdgcn_mfma_f32_16x16x32_f16(Af[mt][0], Bf[0], acc, 0, 0, 0);
        acc = __builtin_amdgcn_mfma_f32_16x16x32_f16(Af[mt][1], Bf[1], acc, 0, 0, 0);
        acc = __builtin_amdgcn_mfma_f32_16x16x32_f16(Af[mt][2], Bf[2], acc, 0, 0, 0);
        acc = __builtin_amdgcn_mfma_f32_16x16x32_f16(Af[mt][3], Bf[3], acc, 0, 0, 0);
        D[mt] = acc;
    }
}

// One substep: prefetch tile it+6 into LDS ring (async DMA, no VGPRs),
// counted vmcnt(20) = 5 tiles in flight (never drain to 0), ds_read next
// tile into the other reg buffer, lgkmcnt(4) + sched_barrier, compute.
#define SUBSTEP(U)  do {                                                          \
    const int it = tt * 8 + (U);                                                  \
    if ((NIT & 7) == 0 || it < NIT) {                                             \
        const int tp = (it + 6 < NIT) ? it + 6 : NIT - 1;                         \
        const size_t tpo = (size_t)TE(tp) << 10;                                  \
        GLOAD16(gl + tpo,       ring + ((((U) + 6) & 7) << 10));                  \
        GLOAD16(gl + tpo + 256, ring + ((((U) + 6) & 7) << 10) + 256);            \
        GLOAD16(gl + tpo + 512, ring + ((((U) + 6) & 7) << 10) + 512);            \
        GLOAD16(gl + tpo + 768, ring + ((((U) + 6) & 7) << 10) + 768);            \
        WAIT_VM(20);                     /* tile it+1 landed in LDS */            \
        DSR128(er[((U) + 1) & 1][0], rb, ((((U) + 1) & 7) * 4096) + 0);           \
        DSR128(er[((U) + 1) & 1][1], rb, ((((U) + 1) & 7) * 4096) + 1024);        \
        DSR128(er[((U) + 1) & 1][2], rb, ((((U) + 1) & 7) * 4096) + 2048);        \
        DSR128(er[((U) + 1) & 1][3], rb, ((((U) + 1) & 7) * 4096) + 3072);        \
        WAIT_LGKM(4);                    /* er[U&1] (current) complete */         \
        __builtin_amdgcn_sched_barrier(0);                                        \
        cstep<FW, NIT, (U) & 3>(it, D, (const uint32*)er[(U) & 1], Af, Lacc, rs); \
    } } while (0)

template <bool FW, int NIT>
__device__ __forceinline__ void chain(const uint32* __restrict__ eo,
                                      const float* __restrict__ trans,
                                      float* __restrict__ ws,
                                      uint32* ring, int cg)
{
    const int l = threadIdx.x & 63;
    const int q = l >> 4, n = l & 15;
    const size_t cgbase = (size_t)cg << 22;
    const uint32* __restrict__ gl = eo + cgbase + (l << 2);   // per-lane DMA src
    const uint32 rb = (uint32)(size_t)(las_u32*)ring + (l << 4); // LDS byte addr

    // exp(A) A-fragments. fwd: D = eA^T*W -> A[m][k]=eA[k][m]; bwd: A[m][k]=eA[m][k]
    h8 Af[8][4];
    #pragma unroll
    for (int mt = 0; mt < 8; ++mt)
        #pragma unroll
        for (int kc = 0; kc < 4; ++kc) {
            h8 a;
            #pragma unroll
            for (int j = 0; j < 8; ++j) {
                const int k = kc * 32 + q * 8 + j;
                const int m = mt * 16 + n;
                a[j] = (half_t)__expf(FW ? trans[k * 128 + m] : trans[m * 128 + k]);
            }
            Af[mt][kc] = a;
        }

    // prologue: issue tiles 0..5 into ring bufs 0..5
    #pragma unroll
    for (int v = 0; v < 6; ++v) {
        const size_t tvo = (size_t)TE(v) << 10;
        #pragma unroll
        for (int k = 0; k < 4; ++k)
            GLOAD16(gl + tvo + (k << 8), ring + (v << 10) + (k << 8));
    }
    WAIT_VM(20);                          // tile 0 landed
    uint4 er[2][4];
    DSR128(er[0][0], rb, 0);
    DSR128(er[0][1], rb, 1024);
    DSR128(er[0][2], rb, 2048);
    DSR128(er[0][3], rb, 3072);

    f4 D[8];
    #pragma unroll
    for (int mt = 0; mt < 8; ++mt) D[mt] = (f4){1.f, 1.f, 1.f, 1.f};
    float Lacc = 0.f, rs = 1.f;

    #pragma unroll 1
    for (int tt = 0; tt < 256; ++tt) {
        SUBSTEP(0); SUBSTEP(1); SUBSTEP(2); SUBSTEP(3);
        SUBSTEP(4); SUBSTEP(5); SUBSTEP(6); SUBSTEP(7);
    }

    float* Xo = ws + (FW ? WX : WQ) + ((cg * 16 + n) << 7);
    #pragma unroll
    for (int mt = 0; mt < 8; ++mt)
        *(f4*)&Xo[mt * 16 + q * 4] = D[mt];
    if (q == 0) ws[(FW ? WLF : WLB) + cg * 16 + n] = Lacc;
}

__global__ __launch_bounds__(64, 1)
void crf_mfma(const uint32* __restrict__ eo, const float* __restrict__ trans,
              float* __restrict__ ws)
{
    __shared__ __align__(16) uint32 ring[8192];   // 8-tile x 4KB LDS ring
    const int bid = blockIdx.x;
    if (bid < 4) chain<true,  2048>(eo, trans, ws, ring, bid);      // eo 0..2047
    else         chain<false, 2047>(eo, trans, ws, ring, bid - 4);  // eo 4095..2049
}

// Z = sum_s X[s]*eo_2048[s]*Q[s]; out = -(log Z + Lf + Lb + 4096*SHIFT16)
__global__ __launch_bounds__(64)
void crf_comb(const float* __restrict__ obs, const float* __restrict__ ws,
              float* __restrict__ out)
{
    const int b = blockIdx.x, l = threadIdx.x;
    const int s0 = 2 * l;
    const float2 o = *(const float2*)&obs[((((size_t)b << 12) + 2048) << 7) + s0];
    const float e0 = __expf(o.x - SHIFT16), e1 = __expf(o.y - SHIFT16);
    float v = ws[WX + b * 128 + s0] * e0 * ws[WQ + b * 128 + s0]
            + ws[WX + b * 128 + s0 + 1] * e1 * ws[WQ + b * 128 + s0 + 1];
    v += __shfl_xor(v, 1);  v += __shfl_xor(v, 2);  v += __shfl_xor(v, 4);
    v += __shfl_xor(v, 8);  v += __shfl_xor(v, 16); v += __shfl_xor(v, 32);
    if (l == 0)
        out[b] = -(__logf(v) + ws[WLF + b] + ws[WLB + b] + 4096.0f * SHIFT16);
}

// ======================= FALLBACK (R3, ws too small) ========================

typedef _Float16 h2f __attribute__((ext_vector_type(2)));
#define FTILE 16
#define FNTILE 128

#if __has_builtin(__builtin_amdgcn_fdot2)
#define FDOT2(p, e, acc) __builtin_amdgcn_fdot2((p), (e), (acc), false)
#else
#define FDOT2(p, e, acc) fmaf((float)(p).x, (float)(e).x, fmaf((float)(p).y, (float)(e).y, (acc)))
#endif

__device__ __forceinline__ h2f u2h(uint32 u) { return __builtin_bit_cast(h2f, u); }
__device__ __forceinline__ uint32 f2h(float f) {
    return (uint32)__builtin_bit_cast(unsigned short, (half_t)f);
}

#define FSTEP(N0, APPLY, MEAS)  do {                                                \
    const int row_ = fw ? ((N0) & (FTILE - 1)) : ((FTILE - 1) - ((N0) & (FTILE - 1))); \
    const float2 o2_ = *(const float2*)&obsL[(((N0) >> 4) & 1) * (FTILE * 128) + (row_ << 7) + (l << 1)]; \
    float e0_ = __expf(o2_.x - SHIFT8);                                             \
    float e1_ = __expf(o2_.y - SHIFT8);                                             \
    if (APPLY) { e0_ *= rsf; e1_ *= rsf; }                                          \
    float w0_, w1_;                                                                 \
    if (fw) { w0_ = pv0; w1_ = pv1; } else { w0_ = pv0 * e0_; w1_ = pv1 * e1_; }    \
    Pl[l] = (f2h(w1_) << 16) | f2h(w0_);                                            \
    float a0_=0.f,a1_=0.f,a2_=0.f,a3_=0.f,b0_=0.f,b1_=0.f,b2_=0.f,b3_=0.f;          \
    _Pragma("unroll")                                                               \
    for (int c_ = 0; c_ < 16; ++c_) {                                               \
        const uint4 q_ = ((const uint4*)Pl)[c_];                                    \
        const h2f p0_ = u2h(q_.x), p1_ = u2h(q_.y), p2_ = u2h(q_.z), p3_ = u2h(q_.w); \
        a0_ = FDOT2(p0_, eA[4*c_+0], a0_);                                          \
        a1_ = FDOT2(p1_, eA[4*c_+1], a1_);                                          \
        a2_ = FDOT2(p2_, eA[4*c_+2], a2_);                                          \
        a3_ = FDOT2(p3_, eA[4*c_+3], a3_);                                          \
        b0_ = FDOT2(p0_, eB[4*c_+0], b0_);                                          \
        b1_ = FDOT2(p1_, eB[4*c_+1], b1_);                                          \
        b2_ = FDOT2(p2_, eB[4*c_+2], b2_);                                          \
        b3_ = FDOT2(p3_, eB[4*c_+3], b3_);                                          \
    }                                                                               \
    const float s0_ = (a0_ + a1_) + (a2_ + a3_);                                    \
    const float s1_ = (b0_ + b1_) + (b2_ + b3_);                                    \
    if (fw) { pv0 = s0_ * e0_; pv1 = s1_ * e1_; } else { pv0 = s0_; pv1 = s1_; }    \
    if (MEAS) {                                                                     \
        float m_ = fmaxf(pv0, pv1);                                                 \
        m_ = fmaxf(m_, __shfl_xor(m_, 1));                                          \
        m_ = fmaxf(m_, __shfl_xor(m_, 2));                                          \
        m_ = fmaxf(m_, __shfl_xor(m_, 4));                                          \
        m_ = fmaxf(m_, __shfl_xor(m_, 8));                                          \
        m_ = fmaxf(m_, __shfl_xor(m_, 16));                                         \
        m_ = fmaxf(m_, __shfl_xor(m_, 32));                                         \
        rsf = __builtin_amdgcn_rcpf(m_);                                            \
        Lacc += __logf(m_);                                                         \
    }                                                                               \
} while (0)

#define FLOADR(TK) do {                                                             \
    const float4* g_ = (const float4*)(obsB + (size_t)(fw ? (TK) * (FTILE * 128)    \
                                      : (4096 - FTILE * ((TK) + 1)) * 128));        \
    r0 = g_[l];       r1 = g_[l + 64];  r2 = g_[l + 128]; r3 = g_[l + 192];         \
    r4 = g_[l + 256]; r5 = g_[l + 320]; r6 = g_[l + 384]; r7 = g_[l + 448];         \
} while (0)

#define FSTORER(TK) do {                                                            \
    float4* s_ = (float4*)&obsL[((TK) & 1) * (FTILE * 128)];                        \
    s_[l] = r0;       s_[l + 64] = r1;  s_[l + 128] = r2; s_[l + 192] = r3;         \
    s_[l + 256] = r4; s_[l + 320] = r5; s_[l + 384] = r6; s_[l + 448] = r7;         \
} while (0)

__global__ __launch_bounds__(64, 1)
void crf_half_fb(const float* __restrict__ obs, const float* __restrict__ trans,
                 float* __restrict__ ws)
{
    __shared__ __align__(16) uint32 Pl[64];
    __shared__ __align__(16) float obsL[2 * FTILE * 128];

    const int l  = threadIdx.x;
    const bool fw = blockIdx.x < 64;
    const int b  = fw ? blockIdx.x : blockIdx.x - 64;
    const float* obsB = obs + (size_t)b * 4096 * 128;

    h2f eA[64], eB[64];
    if (fw) {
        const int c0 = 2 * l;
        #pragma unroll
        for (int k = 0; k < 64; ++k) {
            h2f ta, tb;
            ta.x = (half_t)__expf(trans[(2*k    ) * 128 + c0]);
            ta.y = (half_t)__expf(trans[(2*k + 1) * 128 + c0]);
            tb.x = (half_t)__expf(trans[(2*k    ) * 128 + c0 + 1]);
            tb.y = (half_t)__expf(trans[(2*k + 1) * 128 + c0 + 1]);
            eA[k] = ta; eB[k] = tb;
        }
    } else {
        const int ro0 = (2 * l) * 128, ro1 = (2 * l + 1) * 128;
        #pragma unroll
        for (int k = 0; k < 64; ++k) {
            h2f ta, tb;
            ta.x = (half_t)__expf(trans[ro0 + 2*k]);
            ta.y = (half_t)__expf(trans[ro0 + 2*k + 1]);
            tb.x = (half_t)__expf(trans[ro1 + 2*k]);
            tb.y = (half_t)__expf(trans[ro1 + 2*k + 1]);
            eA[k] = ta; eB[k] = tb;
        }
    }

    float4 r0, r1, r2, r3, r4, r5, r6, r7;
    FLOADR(0);
    FSTORER(0);
    FLOADR(1);

    float rsf = 1.f, Lacc = 0.f, pv0, pv1;

    if (fw) {
        const float2 o2 = *(const float2*)&obsL[l << 1];
        pv0 = __expf(o2.x - SHIFT8);
        pv1 = __expf(o2.y - SHIFT8);
    } else {
        pv0 = 1.f; pv1 = 1.f;
        FSTEP(0, false, false);
    }

    for (int tile = 0; tile < FNTILE; ++tile) {
        if (tile > 0) {
            FSTORER(tile);
            if (tile < FNTILE - 1) FLOADR(tile + 1);
        }
        const int nb = tile << 4;
        #pragma unroll 1
        for (int g = 0; g < 4; ++g) {
            const int n0 = nb + (g << 2);
            if (n0 > 0) FSTEP(n0, true, false);
            FSTEP(n0 + 1, false, false);
            FSTEP(n0 + 2, false, false);
            if (n0 + 3 != 2047) FSTEP(n0 + 3, false, true);
            else                FSTEP(n0 + 3, false, false);
        }
    }

    if (fw) {
        ws[b * 128 + 2*l]     = pv0;
        ws[b * 128 + 2*l + 1] = pv1;
        if (l == 0) ws[16384 + b] = Lacc;
    } else {
        ws[8192 + b * 128 + 2*l]     = pv0;
        ws[8192 + b * 128 + 2*l + 1] = pv1;
        if (l == 0) ws[16448 + b] = Lacc;
    }
}

__global__ __launch_bounds__(64)
void crf_comb_fb(const float* __restrict__ ws, float* __restrict__ out)
{
    const int b = blockIdx.x, l = threadIdx.x;
    float s = ws[b * 128 + 2*l] * ws[8192 + b * 128 + 2*l]
            + ws[b * 128 + 2*l + 1] * ws[8192 + b * 128 + 2*l + 1];
    s += __shfl_xor(s, 1);  s += __shfl_xor(s, 2);  s += __shfl_xor(s, 4);
    s += __shfl_xor(s, 8);  s += __shfl_xor(s, 16); s += __shfl_xor(s, 32);
    if (l == 0)
        out[b] = -(__logf(s) + ws[16384 + b] + ws[16448 + b] + 4096.0f * SHIFT8);
}

// ============================================================================

extern "C" void kernel_launch(void* const* d_in, const int* in_sizes, int n_in,
                              void* d_out, int out_size, void* d_ws, size_t ws_size,
                              hipStream_t stream) {
    (void)in_sizes; (void)n_in; (void)out_size;
    const float* obs   = (const float*)d_in[0];   // [64, 4096, 128] fp32
    const float* trans = (const float*)d_in[1];   // [128, 128] fp32
    float* out = (float*)d_out;                   // [64] fp32
    float* ws  = (float*)d_ws;

    if (ws_size >= (size_t)FAST_WS_BYTES) {
        uint32* eo = (uint32*)((char*)d_ws + EO_BYTE_OFF);
        hipLaunchKernelGGL(eo_prep,  dim3(4096), dim3(256), 0, stream, obs, eo);
        hipLaunchKernelGGL(crf_mfma, dim3(8),    dim3(64),  0, stream, eo, trans, ws);
        hipLaunchKernelGGL(crf_comb, dim3(64),   dim3(64),  0, stream, obs, ws, out);
    } else {
        hipLaunchKernelGGL(crf_half_fb, dim3(128), dim3(64), 0, stream, obs, trans, ws);
        hipLaunchKernelGGL(crf_comb_fb, dim3(64),  dim3(64), 0, stream, ws, out);
    }
}

// Round 3
// 429.265 us; speedup vs baseline: 2.5520x; 2.5520x over previous
//
#include <hip/hip_runtime.h>

typedef _Float16 half_t;
typedef _Float16 h8 __attribute__((ext_vector_type(8)));
typedef _Float16 h2 __attribute__((ext_vector_type(2)));
typedef float f4 __attribute__((ext_vector_type(4)));
typedef unsigned int uint32;
typedef unsigned int u2v __attribute__((ext_vector_type(2)));

#define SHIFT16 2.772588722239781f    // log(16), fast path
#define SHIFT8  2.0794415416798357f   // log(8), fallback path
// ws float offsets:  X[64][128] | Q[64][128] | (legacy Lf/Lb) | pad | eo16
#define WX 0
#define WQ 8192
#define EO_BYTE_OFF 66560u
#define FAST_WS_BYTES (EO_BYTE_OFF + 67108864u)   // eo = 4cg*4096t*64l*64B

typedef const __attribute__((address_space(1))) void gas_void;
typedef __attribute__((address_space(3))) void las_void;
typedef __attribute__((address_space(3))) uint32 las_u32;

// async global->LDS, 16B/lane, no dest VGPRs
#define GLOAD16(gp, lp) \
    __builtin_amdgcn_global_load_lds((gas_void*)(gp), (las_void*)(lp), 16, 0, 0)

#define WAIT_VM(n)   asm volatile("s_waitcnt vmcnt(" #n ")" ::: "memory")
#define WAIT_LGKM(n) asm volatile("s_waitcnt lgkmcnt(" #n ")" ::: "memory")

#define DSR128(dst, addr, imm) \
    asm volatile("ds_read_b128 %0, %1 offset:%2" : "=v"(dst) : "v"(addr), "n"(imm))

__device__ __forceinline__ h2 pkrtz(float a, float b) {
    return __builtin_bit_cast(h2, __builtin_amdgcn_cvt_pkrtz(a, b));
}

// (a,b) <- ([a.lanes0-31 | b.lanes0-31], [a.lanes32-63 | b.lanes32-63])
__device__ __forceinline__ void swap32(uint32& a, uint32& b) {
#if __has_builtin(__builtin_amdgcn_permlane32_swap)
    u2v r = __builtin_amdgcn_permlane32_swap(a, b, false, false);
    a = r.x; b = r.y;
#else
    const uint32 pa = (uint32)__shfl_xor((int)a, 32);
    const uint32 pb = (uint32)__shfl_xor((int)b, 32);
    const bool hi = (threadIdx.x & 32) != 0;
    const uint32 na = hi ? pb : a;
    const uint32 nb = hi ? b : pa;
    a = na; b = nb;
#endif
}
// per 32-lane half: (a,b) <- ([a0-15|b0-15|a32-47|b32-47], [a16-31|b16-31|a48-63|b48-63])
__device__ __forceinline__ void swap16(uint32& a, uint32& b) {
#if __has_builtin(__builtin_amdgcn_permlane16_swap)
    u2v r = __builtin_amdgcn_permlane16_swap(a, b, false, false);
    a = r.x; b = r.y;
#else
    const uint32 sa = (uint32)__builtin_amdgcn_ds_swizzle((int)a, 0x401F);
    const uint32 sb = (uint32)__builtin_amdgcn_ds_swizzle((int)b, 0x401F);
    const bool m = (threadIdx.x & 16) != 0;
    const uint32 na = m ? sb : a;
    const uint32 nb = m ? b : sa;
    a = na; b = nb;
#endif
}

// pure-VALU wave max over lane bits 4 and 5
__device__ __forceinline__ float wavemax_hi(float M) {
    uint32 ma = __builtin_bit_cast(uint32, M), mb = ma;
    swap16(ma, mb);
    M = fmaxf(__builtin_bit_cast(float, ma), __builtin_bit_cast(float, mb));
    ma = __builtin_bit_cast(uint32, M); mb = ma;
    swap32(ma, mb);
    return fmaxf(__builtin_bit_cast(float, ma), __builtin_bit_cast(float, mb));
}

// pure-VALU wave sum over lane bits 4 and 5 (sums the 4 q-lanes of a chain)
__device__ __forceinline__ float wavesum_hi(float S) {
    uint32 a = __builtin_bit_cast(uint32, S), b = a;
    swap16(a, b);
    S = __builtin_bit_cast(float, a) + __builtin_bit_cast(float, b);
    a = __builtin_bit_cast(uint32, S); b = a;
    swap32(a, b);
    return __builtin_bit_cast(float, a) + __builtin_bit_cast(float, b);
}

// per-chain sum of the 128-state vector held in D (across mt, elems, q-lanes)
__device__ __forceinline__ float chain_sum(const f4 (&D)[8]) {
    f4 s4 = (D[0] + D[1]) + (D[2] + D[3]);
    s4 = s4 + ((D[4] + D[5]) + (D[6] + D[7]));
    float S = (s4.x + s4.y) + (s4.z + s4.w);
    return wavesum_hi(S);
}

// ============================ FAST PATH =====================================

// eo16[cg][t][g 0..3][lane l]: fp16 exp(obs-SHIFT16) pairs in MFMA D-layout
// order, tile-transposed so consumer ds_read_b128 #j at byte j*1024+l*16 is
// contiguous.
__global__ __launch_bounds__(256)
void eo_prep(const float* __restrict__ obs, uint32* __restrict__ eo)
{
    __shared__ float sb[64 * 130];       // 64 rows (n,tl) x 128 floats, padded
    const int tid = threadIdx.x;
    const int cg = blockIdx.x >> 10;     // 4 chain-groups
    const int tb = blockIdx.x & 1023;    // 1024 blocks of 4 timesteps

    #pragma unroll
    for (int i = 0; i < 8; ++i) {        // load 64x128 floats, coalesced
        const int idx = i * 256 + tid;   // 2048 float4s
        const int row = idx >> 5, c4 = idx & 31;
        const int n = row >> 2, tl = row & 3;
        const float4 v = *(const float4*)
            &obs[((size_t)(cg * 16 + n) * 4096 + (tb * 4 + tl)) * 128 + c4 * 4];
        *(float4*)&sb[row * 130 + c4 * 4] = v;
    }
    __syncthreads();

    const int gg = tid >> 6;             // dword-group 0..3
    const int l  = tid & 63;             // output lane 0..63
    const int q = l >> 4, nn = l & 15;
    #pragma unroll
    for (int tl = 0; tl < 4; ++tl) {
        uint4 o;
        uint32* po = &o.x;
        #pragma unroll
        for (int j = 0; j < 4; ++j) {
            const int hd = gg * 4 + j;
            const int mt = hd >> 1, rr = (hd & 1) * 2;
            const int s = mt * 16 + q * 4 + rr;
            const float* p = &sb[(nn * 4 + tl) * 130 + s];
            po[j] = __builtin_bit_cast(uint32,
                      pkrtz(__expf(p[0] - SHIFT16), __expf(p[1] - SHIFT16)));
        }
        *(uint4*)&eo[((size_t)(cg * 4096 + tb * 4 + tl) << 10) + (gg << 8) + (l << 2)] = o;
    }
}

#define TE(N) (FW ? (N) : (4095 - (N)))
#define WSEG 256     // warmup substeps
#define LSEG 256     // main substeps per segment (C = 2048/LSEG = 8)
#define NSEG 8

template <bool FW, int ST>
__device__ __forceinline__ void cstep(int v, int nv, bool head,
                                      f4 (&D)[8], const uint32* ep,
                                      const h8 (&Af)[8][4],
                                      float& Lacc, float& rs, float& saK)
{
    const f4 Z = {0.f, 0.f, 0.f, 0.f};

    if (ST == 0) {                       // apply pending renorm (fp32, exact)
        #pragma unroll
        for (int mt = 0; mt < 8; ++mt) D[mt] = D[mt] * rs;
        if (v == WSEG) {                 // segment boundary: end of warmup
            if (head) {                  // exact chain head: true init
                #pragma unroll
                for (int mt = 0; mt < 8; ++mt) D[mt] = (f4){1.f, 1.f, 1.f, 1.f};
            } else {
                saK = chain_sum(D);      // warm-start direction sum (per chain)
            }
            Lacc = 0.f;                  // discard warmup scale bookkeeping
        }
    }
    if (ST == 3) {
        if (v != nv - 1) {               // measure; pure VALU (permlane max)
            f4 m01 = __builtin_elementwise_max(D[0], D[1]);
            f4 m23 = __builtin_elementwise_max(D[2], D[3]);
            f4 m45 = __builtin_elementwise_max(D[4], D[5]);
            f4 m67 = __builtin_elementwise_max(D[6], D[7]);
            f4 ma = __builtin_elementwise_max(
                        __builtin_elementwise_max(m01, m23),
                        __builtin_elementwise_max(m45, m67));
            float M = fmaxf(fmaxf(ma.x, ma.y), fmaxf(ma.z, ma.w));
            M = wavemax_hi(M);
            Lacc += __logf(M);
            rs = __builtin_amdgcn_rcpf(M);
        }
    }

    // pack W = fp16(D) * eo  (register-resident)
    uint32 Wx[8], Wy[8];
    #pragma unroll
    for (int mt = 0; mt < 8; ++mt) {
        h2 w0 = pkrtz(D[mt].x, D[mt].y) * __builtin_bit_cast(h2, ep[2 * mt]);
        h2 w1 = pkrtz(D[mt].z, D[mt].w) * __builtin_bit_cast(h2, ep[2 * mt + 1]);
        Wx[mt] = __builtin_bit_cast(uint32, w0);
        Wy[mt] = __builtin_bit_cast(uint32, w1);
    }

    // cross-lane permute D-layout -> B-fragment layout (no LDS)
    h8 Bf[4];
    #pragma unroll
    for (int kc = 0; kc < 4; ++kc) {
        uint32 x0 = Wx[2 * kc], x1 = Wx[2 * kc + 1];
        uint32 y0 = Wy[2 * kc], y1 = Wy[2 * kc + 1];
        swap32(x0, x1); swap16(x0, x1);   // x0=d0, x1=d2
        swap32(y0, y1); swap16(y0, y1);   // y0=d1, y1=d3
        uint4 bv; bv.x = x0; bv.y = y0; bv.z = x1; bv.w = y1;
        Bf[kc] = __builtin_bit_cast(h8, bv);
    }

    // 32 MFMAs: 8 independent mt chains of depth 4
    #pragma unroll
    for (int mt = 0; mt < 8; ++mt) {
        f4 acc = Z;
        acc = __builtin_amdgcn_mfma_f32_16x16x32_f16(Af[mt][0], Bf[0], acc, 0, 0, 0);
        acc = __builtin_amdgcn_mfma_f32_16x16x32_f16(Af[mt][1], Bf[1], acc, 0, 0, 0);
        acc = __builtin_amdgcn_mfma_f32_16x16x32_f16(Af[mt][2], Bf[2], acc, 0, 0, 0);
        acc = __builtin_amdgcn_mfma_f32_16x16x32_f16(Af[mt][3], Bf[3], acc, 0, 0, 0);
        D[mt] = acc;
    }
}

// One substep: prefetch tile v+6 into LDS ring (async DMA), counted vmcnt(20),
// ds_read next tile into the other reg buffer, lgkmcnt(4) + sched_barrier.
#define SUBSTEP(U)  do {                                                          \
    const int v_ = tt * 8 + (U);                                                  \
    if (v_ < nv) {                                                                \
        int ip_ = itb + v_ + 6;                                                   \
        ip_ = ip_ < 0 ? 0 : (ip_ > NITd - 1 ? NITd - 1 : ip_);                    \
        const size_t tpo_ = (size_t)TE(ip_) << 10;                                \
        GLOAD16(gl + tpo_,       ring + ((((U) + 6) & 7) << 10));                 \
        GLOAD16(gl + tpo_ + 256, ring + ((((U) + 6) & 7) << 10) + 256);           \
        GLOAD16(gl + tpo_ + 512, ring + ((((U) + 6) & 7) << 10) + 512);           \
        GLOAD16(gl + tpo_ + 768, ring + ((((U) + 6) & 7) << 10) + 768);           \
        WAIT_VM(20);                     /* tile v+1 landed in LDS */             \
        DSR128(er[((U) + 1) & 1][0], rb, ((((U) + 1) & 7) * 4096) + 0);           \
        DSR128(er[((U) + 1) & 1][1], rb, ((((U) + 1) & 7) * 4096) + 1024);        \
        DSR128(er[((U) + 1) & 1][2], rb, ((((U) + 1) & 7) * 4096) + 2048);        \
        DSR128(er[((U) + 1) & 1][3], rb, ((((U) + 1) & 7) * 4096) + 3072);        \
        WAIT_LGKM(4);                    /* er[U&1] (current) complete */         \
        __builtin_amdgcn_sched_barrier(0);                                        \
        cstep<FW, (U) & 3>(v_, nv, head, D, (const uint32*)er[(U) & 1],           \
                           Af, Lacc, rs, saK);                                    \
    } } while (0)

template <bool FW>
__device__ __forceinline__ void chain(uint32* __restrict__ eo,
                                      const float* __restrict__ trans,
                                      float* __restrict__ ws,
                                      uint32* ring, int cg, int sg)
{
    const int l = threadIdx.x & 63;
    const int q = l >> 4, n = l & 15;
    const int NITd = FW ? 2048 : 2047;
    const int nv   = (!FW && sg == NSEG - 1) ? (WSEG + LSEG - 1) : (WSEG + LSEG);
    const bool head = (sg == 0);
    const bool mid  = (sg == NSEG - 1);
    const int itb = (sg - 1) * LSEG;     // global it = itb + v
    const size_t cgbase = (size_t)cg << 22;
    const uint32* __restrict__ gl = eo + cgbase + (l << 2);   // per-lane DMA src
    const uint32 rb = (uint32)(size_t)(las_u32*)ring + (l << 4);

    // exp(A) A-fragments. fwd: D = eA^T*W -> A[m][k]=eA[k][m]; bwd: A[m][k]=eA[m][k]
    h8 Af[8][4];
    #pragma unroll
    for (int mt = 0; mt < 8; ++mt)
        #pragma unroll
        for (int kc = 0; kc < 4; ++kc) {
            h8 a;
            #pragma unroll
            for (int j = 0; j < 8; ++j) {
                const int k = kc * 32 + q * 8 + j;
                const int m = mt * 16 + n;
                a[j] = (half_t)__expf(FW ? trans[k * 128 + m] : trans[m * 128 + k]);
            }
            Af[mt][kc] = a;
        }

    // prologue: issue tiles v=0..5 into ring bufs 0..5
    #pragma unroll
    for (int vv = 0; vv < 6; ++vv) {
        int ip = itb + vv;
        ip = ip < 0 ? 0 : (ip > NITd - 1 ? NITd - 1 : ip);
        const size_t tvo = (size_t)TE(ip) << 10;
        #pragma unroll
        for (int k = 0; k < 4; ++k)
            GLOAD16(gl + tvo + (k << 8), ring + (vv << 10) + (k << 8));
    }
    WAIT_VM(20);                          // tile 0 landed
    uint4 er[2][4];
    DSR128(er[0][0], rb, 0);
    DSR128(er[0][1], rb, 1024);
    DSR128(er[0][2], rb, 2048);
    DSR128(er[0][3], rb, 3072);

    f4 D[8];
    #pragma unroll
    for (int mt = 0; mt < 8; ++mt) D[mt] = (f4){1.f, 1.f, 1.f, 1.f};
    float Lacc = 0.f, rs = 1.f, saK = 1.f;

    #pragma unroll 1
    for (int tt = 0; tt < (WSEG + LSEG) / 8; ++tt) {
        SUBSTEP(0); SUBSTEP(1); SUBSTEP(2); SUBSTEP(3);
        SUBSTEP(4); SUBSTEP(5); SUBSTEP(6); SUBSTEP(7);
    }

    // epilogue: midpoint waves store the state tile; all waves store scalars
    const float swK = chain_sum(D);
    if (mid) {
        float* Xo = ws + (FW ? WX : WQ) + ((cg * 16 + n) << 7);
        #pragma unroll
        for (int mt = 0; mt < 8; ++mt)
            *(f4*)&Xo[mt * 16 + q * 4] = D[mt];
    }
    // scalars live in the never-read eo tile t=2048 of this cg:
    // per cg: [dir 2][ L[8][16] | sw[8][16] | sa[8][16] ] floats
    float* sc = (float*)eo + ((size_t)(cg * 4096 + 2048) << 10) + (FW ? 0 : 384);
    if (q == 0) {
        sc[sg * 16 + n]       = Lacc;
        sc[128 + sg * 16 + n] = swK;
        sc[256 + sg * 16 + n] = head ? 1.0f : saK;
    }
}

__global__ __launch_bounds__(64, 1)
void crf_mfma(uint32* __restrict__ eo, const float* __restrict__ trans,
              float* __restrict__ ws)
{
    __shared__ __align__(16) uint32 ring[8192];   // 8-tile x 4KB LDS ring
    const int bid = blockIdx.x;                   // 64 blocks: dir*32 + cg*8 + sg
    const int r = bid & 31;
    const int cg = r >> 3, sg = r & 7;
    if (bid < 32) chain<true >(eo, trans, ws, ring, cg, sg);
    else          chain<false>(eo, trans, ws, ring, cg, sg);
}

// Z = sum_s X[s]*eo_2048[s]*Q[s]; out = -(log Z + corrections + 4096*SHIFT16)
// corrections: per dir: sum_s L_s + sum_{s>=1} [log sw_{s-1} - log sa_s]
__global__ __launch_bounds__(64)
void crf_comb(const float* __restrict__ obs, const float* __restrict__ ws,
              const float* __restrict__ scb, float* __restrict__ out)
{
    const int b = blockIdx.x, l = threadIdx.x;
    const int cg = b >> 4, n = b & 15;
    const int s0 = 2 * l;
    const float2 o = *(const float2*)&obs[((((size_t)b << 12) + 2048) << 7) + s0];
    const float e0 = __expf(o.x - SHIFT16), e1 = __expf(o.y - SHIFT16);
    float v = ws[WX + b * 128 + s0] * e0 * ws[WQ + b * 128 + s0]
            + ws[WX + b * 128 + s0 + 1] * e1 * ws[WQ + b * 128 + s0 + 1];
    v += __shfl_xor(v, 1);  v += __shfl_xor(v, 2);  v += __shfl_xor(v, 4);
    v += __shfl_xor(v, 8);  v += __shfl_xor(v, 16); v += __shfl_xor(v, 32);
    if (l == 0) {
        float corr = 0.f;
        #pragma unroll
        for (int dir = 0; dir < 2; ++dir) {
            const float* sc = scb + ((size_t)(cg * 4096 + 2048) << 10) + dir * 384;
            #pragma unroll
            for (int s = 0; s < NSEG; ++s) corr += sc[s * 16 + n];
            #pragma unroll
            for (int s = 1; s < NSEG; ++s)
                corr += __logf(sc[128 + (s - 1) * 16 + n])
                      - __logf(sc[256 + s * 16 + n]);
        }
        out[b] = -(__logf(v) + corr + 4096.0f * SHIFT16);
    }
}

// ======================= FALLBACK (R3, ws too small) ========================

typedef _Float16 h2f __attribute__((ext_vector_type(2)));
#define FTILE 16
#define FNTILE 128

#if __has_builtin(__builtin_amdgcn_fdot2)
#define FDOT2(p, e, acc) __builtin_amdgcn_fdot2((p), (e), (acc), false)
#else
#define FDOT2(p, e, acc) fmaf((float)(p).x, (float)(e).x, fmaf((float)(p).y, (float)(e).y, (acc)))
#endif

__device__ __forceinline__ h2f u2h(uint32 u) { return __builtin_bit_cast(h2f, u); }
__device__ __forceinline__ uint32 f2h(float f) {
    return (uint32)__builtin_bit_cast(unsigned short, (half_t)f);
}

#define FSTEP(N0, APPLY, MEAS)  do {                                                \
    const int row_ = fw ? ((N0) & (FTILE - 1)) : ((FTILE - 1) - ((N0) & (FTILE - 1))); \
    const float2 o2_ = *(const float2*)&obsL[(((N0) >> 4) & 1) * (FTILE * 128) + (row_ << 7) + (l << 1)]; \
    float e0_ = __expf(o2_.x - SHIFT8);                                             \
    float e1_ = __expf(o2_.y - SHIFT8);                                             \
    if (APPLY) { e0_ *= rsf; e1_ *= rsf; }                                          \
    float w0_, w1_;                                                                 \
    if (fw) { w0_ = pv0; w1_ = pv1; } else { w0_ = pv0 * e0_; w1_ = pv1 * e1_; }    \
    Pl[l] = (f2h(w1_) << 16) | f2h(w0_);                                            \
    float a0_=0.f,a1_=0.f,a2_=0.f,a3_=0.f,b0_=0.f,b1_=0.f,b2_=0.f,b3_=0.f;          \
    _Pragma("unroll")                                                               \
    for (int c_ = 0; c_ < 16; ++c_) {                                               \
        const uint4 q_ = ((const uint4*)Pl)[c_];                                    \
        const h2f p0_ = u2h(q_.x), p1_ = u2h(q_.y), p2_ = u2h(q_.z), p3_ = u2h(q_.w); \
        a0_ = FDOT2(p0_, eA[4*c_+0], a0_);                                          \
        a1_ = FDOT2(p1_, eA[4*c_+1], a1_);                                          \
        a2_ = FDOT2(p2_, eA[4*c_+2], a2_);                                          \
        a3_ = FDOT2(p3_, eA[4*c_+3], a3_);                                          \
        b0_ = FDOT2(p0_, eB[4*c_+0], b0_);                                          \
        b1_ = FDOT2(p1_, eB[4*c_+1], b1_);                                          \
        b2_ = FDOT2(p2_, eB[4*c_+2], b2_);                                          \
        b3_ = FDOT2(p3_, eB[4*c_+3], b3_);                                          \
    }                                                                               \
    const float s0_ = (a0_ + a1_) + (a2_ + a3_);                                    \
    const float s1_ = (b0_ + b1_) + (b2_ + b3_);                                    \
    if (fw) { pv0 = s0_ * e0_; pv1 = s1_ * e1_; } else { pv0 = s0_; pv1 = s1_; }    \
    if (MEAS) {                                                                     \
        float m_ = fmaxf(pv0, pv1);                                                 \
        m_ = fmaxf(m_, __shfl_xor(m_, 1));                                          \
        m_ = fmaxf(m_, __shfl_xor(m_, 2));                                          \
        m_ = fmaxf(m_, __shfl_xor(m_, 4));                                          \
        m_ = fmaxf(m_, __shfl_xor(m_, 8));                                          \
        m_ = fmaxf(m_, __shfl_xor(m_, 16));                                         \
        m_ = fmaxf(m_, __shfl_xor(m_, 32));                                         \
        rsf = __builtin_amdgcn_rcpf(m_);                                            \
        Lacc += __logf(m_);                                                         \
    }                                                                               \
} while (0)

#define FLOADR(TK) do {                                                             \
    const float4* g_ = (const float4*)(obsB + (size_t)(fw ? (TK) * (FTILE * 128)    \
                                      : (4096 - FTILE * ((TK) + 1)) * 128));        \
    r0 = g_[l];       r1 = g_[l + 64];  r2 = g_[l + 128]; r3 = g_[l + 192];         \
    r4 = g_[l + 256]; r5 = g_[l + 320]; r6 = g_[l + 384]; r7 = g_[l + 448];         \
} while (0)

#define FSTORER(TK) do {                                                            \
    float4* s_ = (float4*)&obsL[((TK) & 1) * (FTILE * 128)];                        \
    s_[l] = r0;       s_[l + 64] = r1;  s_[l + 128] = r2; s_[l + 192] = r3;         \
    s_[l + 256] = r4; s_[l + 320] = r5; s_[l + 384] = r6; s_[l + 448] = r7;         \
} while (0)

__global__ __launch_bounds__(64, 1)
void crf_half_fb(const float* __restrict__ obs, const float* __restrict__ trans,
                 float* __restrict__ ws)
{
    __shared__ __align__(16) uint32 Pl[64];
    __shared__ __align__(16) float obsL[2 * FTILE * 128];

    const int l  = threadIdx.x;
    const bool fw = blockIdx.x < 64;
    const int b  = fw ? blockIdx.x : blockIdx.x - 64;
    const float* obsB = obs + (size_t)b * 4096 * 128;

    h2f eA[64], eB[64];
    if (fw) {
        const int c0 = 2 * l;
        #pragma unroll
        for (int k = 0; k < 64; ++k) {
            h2f ta, tb;
            ta.x = (half_t)__expf(trans[(2*k    ) * 128 + c0]);
            ta.y = (half_t)__expf(trans[(2*k + 1) * 128 + c0]);
            tb.x = (half_t)__expf(trans[(2*k    ) * 128 + c0 + 1]);
            tb.y = (half_t)__expf(trans[(2*k + 1) * 128 + c0 + 1]);
            eA[k] = ta; eB[k] = tb;
        }
    } else {
        const int ro0 = (2 * l) * 128, ro1 = (2 * l + 1) * 128;
        #pragma unroll
        for (int k = 0; k < 64; ++k) {
            h2f ta, tb;
            ta.x = (half_t)__expf(trans[ro0 + 2*k]);
            ta.y = (half_t)__expf(trans[ro0 + 2*k + 1]);
            tb.x = (half_t)__expf(trans[ro1 + 2*k]);
            tb.y = (half_t)__expf(trans[ro1 + 2*k + 1]);
            eA[k] = ta; eB[k] = tb;
        }
    }

    float4 r0, r1, r2, r3, r4, r5, r6, r7;
    FLOADR(0);
    FSTORER(0);
    FLOADR(1);

    float rsf = 1.f, Lacc = 0.f, pv0, pv1;

    if (fw) {
        const float2 o2 = *(const float2*)&obsL[l << 1];
        pv0 = __expf(o2.x - SHIFT8);
        pv1 = __expf(o2.y - SHIFT8);
    } else {
        pv0 = 1.f; pv1 = 1.f;
        FSTEP(0, false, false);
    }

    for (int tile = 0; tile < FNTILE; ++tile) {
        if (tile > 0) {
            FSTORER(tile);
            if (tile < FNTILE - 1) FLOADR(tile + 1);
        }
        const int nb = tile << 4;
        #pragma unroll 1
        for (int g = 0; g < 4; ++g) {
            const int n0 = nb + (g << 2);
            if (n0 > 0) FSTEP(n0, true, false);
            FSTEP(n0 + 1, false, false);
            FSTEP(n0 + 2, false, false);
            if (n0 + 3 != 2047) FSTEP(n0 + 3, false, true);
            else                FSTEP(n0 + 3, false, false);
        }
    }

    if (fw) {
        ws[b * 128 + 2*l]     = pv0;
        ws[b * 128 + 2*l + 1] = pv1;
        if (l == 0) ws[16384 + b] = Lacc;
    } else {
        ws[8192 + b * 128 + 2*l]     = pv0;
        ws[8192 + b * 128 + 2*l + 1] = pv1;
        if (l == 0) ws[16448 + b] = Lacc;
    }
}

__global__ __launch_bounds__(64)
void crf_comb_fb(const float* __restrict__ ws, float* __restrict__ out)
{
    const int b = blockIdx.x, l = threadIdx.x;
    float s = ws[b * 128 + 2*l] * ws[8192 + b * 128 + 2*l]
            + ws[b * 128 + 2*l + 1] * ws[8192 + b * 128 + 2*l + 1];
    s += __shfl_xor(s, 1);  s += __shfl_xor(s, 2);  s += __shfl_xor(s, 4);
    s += __shfl_xor(s, 8);  s += __shfl_xor(s, 16); s += __shfl_xor(s, 32);
    if (l == 0)
        out[b] = -(__logf(s) + ws[16384 + b] + ws[16448 + b] + 4096.0f * SHIFT8);
}

// ============================================================================

extern "C" void kernel_launch(void* const* d_in, const int* in_sizes, int n_in,
                              void* d_out, int out_size, void* d_ws, size_t ws_size,
                              hipStream_t stream) {
    (void)in_sizes; (void)n_in; (void)out_size;
    const float* obs   = (const float*)d_in[0];   // [64, 4096, 128] fp32
    const float* trans = (const float*)d_in[1];   // [128, 128] fp32
    float* out = (float*)d_out;                   // [64] fp32
    float* ws  = (float*)d_ws;

    if (ws_size >= (size_t)FAST_WS_BYTES) {
        uint32* eo = (uint32*)((char*)d_ws + EO_BYTE_OFF);
        hipLaunchKernelGGL(eo_prep,  dim3(4096), dim3(256), 0, stream, obs, eo);
        hipLaunchKernelGGL(crf_mfma, dim3(64),   dim3(64),  0, stream, eo, trans, ws);
        hipLaunchKernelGGL(crf_comb, dim3(64),   dim3(64),  0, stream, obs, ws,
                           (const float*)eo, out);
    } else {
        hipLaunchKernelGGL(crf_half_fb, dim3(128), dim3(64), 0, stream, obs, trans, ws);
        hipLaunchKernelGGL(crf_comb_fb, dim3(64),  dim3(64), 0, stream, ws, out);
    }
}

// Round 4
// 335.687 us; speedup vs baseline: 3.2634x; 1.2788x over previous
//
#include <hip/hip_runtime.h>

typedef _Float16 half_t;
typedef _Float16 h8 __attribute__((ext_vector_type(8)));
typedef _Float16 h2 __attribute__((ext_vector_type(2)));
typedef float f4 __attribute__((ext_vector_type(4)));
typedef unsigned int uint32;
typedef unsigned long long u64;
typedef unsigned int u2v __attribute__((ext_vector_type(2)));

#define SHIFT16 2.772588722239781f    // log(16), fast path
#define SHIFT8  2.0794415416798357f   // log(8), fallback path
// ws float offsets: X[64][128] | Q[64][128] | scalars[4cg][2dir][3][16seg][16n]
#define WX 0
#define WQ 8192
#define WSC 16384
#define FAST_WS_BYTES 90112u          // 22528 floats

#define WAIT_VM(n)   asm volatile("s_waitcnt vmcnt(" #n ")" ::: "memory")

// inline-asm global load: program-order issue, counted vmcnt, can't be sunk
#define GL4(dst, addr, OFFSTR) \
    asm volatile("global_load_dwordx4 %0, %1, off offset:" OFFSTR \
                 : "=v"(dst) : "v"(addr))

__device__ __forceinline__ h2 pkrtz(float a, float b) {
    return __builtin_bit_cast(h2, __builtin_amdgcn_cvt_pkrtz(a, b));
}

// (a,b) <- ([a.lanes0-31 | b.lanes0-31], [a.lanes32-63 | b.lanes32-63])
__device__ __forceinline__ void swap32(uint32& a, uint32& b) {
#if __has_builtin(__builtin_amdgcn_permlane32_swap)
    u2v r = __builtin_amdgcn_permlane32_swap(a, b, false, false);
    a = r.x; b = r.y;
#else
    const uint32 pa = (uint32)__shfl_xor((int)a, 32);
    const uint32 pb = (uint32)__shfl_xor((int)b, 32);
    const bool hi = (threadIdx.x & 32) != 0;
    const uint32 na = hi ? pb : a;
    const uint32 nb = hi ? b : pa;
    a = na; b = nb;
#endif
}
// per 32-lane half: (a,b) <- ([a0-15|b0-15|a32-47|b32-47], [a16-31|b16-31|a48-63|b48-63])
__device__ __forceinline__ void swap16(uint32& a, uint32& b) {
#if __has_builtin(__builtin_amdgcn_permlane16_swap)
    u2v r = __builtin_amdgcn_permlane16_swap(a, b, false, false);
    a = r.x; b = r.y;
#else
    const uint32 sa = (uint32)__builtin_amdgcn_ds_swizzle((int)a, 0x401F);
    const uint32 sb = (uint32)__builtin_amdgcn_ds_swizzle((int)b, 0x401F);
    const bool m = (threadIdx.x & 16) != 0;
    const uint32 na = m ? sb : a;
    const uint32 nb = m ? b : sa;
    a = na; b = nb;
#endif
}

// pure-VALU wave max over lane bits 4 and 5
__device__ __forceinline__ float wavemax_hi(float M) {
    uint32 ma = __builtin_bit_cast(uint32, M), mb = ma;
    swap16(ma, mb);
    M = fmaxf(__builtin_bit_cast(float, ma), __builtin_bit_cast(float, mb));
    ma = __builtin_bit_cast(uint32, M); mb = ma;
    swap32(ma, mb);
    return fmaxf(__builtin_bit_cast(float, ma), __builtin_bit_cast(float, mb));
}

// pure-VALU wave sum over lane bits 4 and 5 (sums the 4 q-lanes of a chain)
__device__ __forceinline__ float wavesum_hi(float S) {
    uint32 a = __builtin_bit_cast(uint32, S), b = a;
    swap16(a, b);
    S = __builtin_bit_cast(float, a) + __builtin_bit_cast(float, b);
    a = __builtin_bit_cast(uint32, S); b = a;
    swap32(a, b);
    return __builtin_bit_cast(float, a) + __builtin_bit_cast(float, b);
}

// per-chain sum of the 128-state vector held in D (across mt, elems, q-lanes)
__device__ __forceinline__ float chain_sum(const f4 (&D)[8]) {
    f4 s4 = (D[0] + D[1]) + (D[2] + D[3]);
    s4 = s4 + ((D[4] + D[5]) + (D[6] + D[7]));
    float S = (s4.x + s4.y) + (s4.z + s4.w);
    return wavesum_hi(S);
}

// ============================ FAST PATH =====================================

#define TE(N) (FW ? (N) : (4095 - (N)))
#define WSEG 128     // warmup substeps
#define LSEG 128     // main substeps per segment (C = 2048/LSEG = 16)
#define NSEG 16

template <bool FW, int ST>
__device__ __forceinline__ void cstep(int v, int nv, bool head,
                                      f4 (&D)[8], const uint32 (&ep)[16],
                                      const h8 (&Af)[8][4],
                                      float& Lacc, float& rs, float& saK)
{
    const f4 Z = {0.f, 0.f, 0.f, 0.f};

    if (ST == 0) {                       // apply pending renorm (fp32, exact)
        #pragma unroll
        for (int mt = 0; mt < 8; ++mt) D[mt] = D[mt] * rs;
        if (v == WSEG) {                 // segment boundary: end of warmup
            if (head) {                  // exact chain head: true init
                #pragma unroll
                for (int mt = 0; mt < 8; ++mt) D[mt] = (f4){1.f, 1.f, 1.f, 1.f};
            } else {
                saK = chain_sum(D);      // warm-start direction sum (per chain)
            }
            Lacc = 0.f;                  // discard warmup scale bookkeeping
        }
    }
    if (ST == 3) {
        if (v != nv - 1) {               // measure; pure VALU (permlane max)
            f4 m01 = __builtin_elementwise_max(D[0], D[1]);
            f4 m23 = __builtin_elementwise_max(D[2], D[3]);
            f4 m45 = __builtin_elementwise_max(D[4], D[5]);
            f4 m67 = __builtin_elementwise_max(D[6], D[7]);
            f4 ma = __builtin_elementwise_max(
                        __builtin_elementwise_max(m01, m23),
                        __builtin_elementwise_max(m45, m67));
            float M = fmaxf(fmaxf(ma.x, ma.y), fmaxf(ma.z, ma.w));
            M = wavemax_hi(M);
            Lacc += __logf(M);
            rs = __builtin_amdgcn_rcpf(M);
        }
    }

    // pack W = fp16(D) * eo  (register-resident)
    uint32 Wx[8], Wy[8];
    #pragma unroll
    for (int mt = 0; mt < 8; ++mt) {
        h2 w0 = pkrtz(D[mt].x, D[mt].y) * __builtin_bit_cast(h2, ep[2 * mt]);
        h2 w1 = pkrtz(D[mt].z, D[mt].w) * __builtin_bit_cast(h2, ep[2 * mt + 1]);
        Wx[mt] = __builtin_bit_cast(uint32, w0);
        Wy[mt] = __builtin_bit_cast(uint32, w1);
    }

    // cross-lane permute D-layout -> B-fragment layout (no LDS)
    h8 Bf[4];
    #pragma unroll
    for (int kc = 0; kc < 4; ++kc) {
        uint32 x0 = Wx[2 * kc], x1 = Wx[2 * kc + 1];
        uint32 y0 = Wy[2 * kc], y1 = Wy[2 * kc + 1];
        swap32(x0, x1); swap16(x0, x1);   // x0=d0, x1=d2
        swap32(y0, y1); swap16(y0, y1);   // y0=d1, y1=d3
        uint4 bv; bv.x = x0; bv.y = y0; bv.z = x1; bv.w = y1;
        Bf[kc] = __builtin_bit_cast(h8, bv);
    }

    // 32 MFMAs: 8 independent mt chains of depth 4
    #pragma unroll
    for (int mt = 0; mt < 8; ++mt) {
        f4 acc = Z;
        acc = __builtin_amdgcn_mfma_f32_16x16x32_f16(Af[mt][0], Bf[0], acc, 0, 0, 0);
        acc = __builtin_amdgcn_mfma_f32_16x16x32_f16(Af[mt][1], Bf[1], acc, 0, 0, 0);
        acc = __builtin_amdgcn_mfma_f32_16x16x32_f16(Af[mt][2], Bf[2], acc, 0, 0, 0);
        acc = __builtin_amdgcn_mfma_f32_16x16x32_f16(Af[mt][3], Bf[3], acc, 0, 0, 0);
        D[mt] = acc;
    }
}

// Issue 8 gather-loads of lane's 32 states (chain n, timestep ip) into G[B].
// Lane l=q*16+n reads float4 at state offset mt*16+q*4 -> ep[2mt],ep[2mt+1].
#define ISSUE8(B, IPE) do {                                                   \
    int ip_ = (IPE);                                                          \
    ip_ = ip_ < 0 ? 0 : (ip_ > NITd - 1 ? NITd - 1 : ip_);                    \
    const u64 a_ = lbase + ((u64)TE(ip_) << 9);                               \
    GL4(G[B][0], a_, "0");   GL4(G[B][1], a_, "64");                          \
    GL4(G[B][2], a_, "128"); GL4(G[B][3], a_, "192");                         \
    GL4(G[B][4], a_, "256"); GL4(G[B][5], a_, "320");                         \
    GL4(G[B][6], a_, "384"); GL4(G[B][7], a_, "448");                         \
} while (0)

// One substep: issue tile v+2 (depth-2 prefetch, counted vmcnt), wait for
// tile v (vmcnt(16) = 2 tiles x 8 loads still in flight), exp+pack, compute.
#define SUBSTEP(U)  do {                                                      \
    const int v_ = tt * 8 + (U);                                              \
    if (v_ < nv) {                                                            \
        ISSUE8(((U) + 2) & 3, itb + v_ + 2);                                  \
        WAIT_VM(16);                     /* tile v landed in G[U&3] */        \
        __builtin_amdgcn_sched_barrier(0);                                    \
        uint32 ep[16];                                                        \
        _Pragma("unroll")                                                     \
        for (int mt = 0; mt < 8; ++mt) {                                      \
            const f4 ov = __builtin_bit_cast(f4, G[(U) & 3][mt]);             \
            ep[2 * mt] = __builtin_bit_cast(uint32,                           \
                pkrtz(__expf(ov.x - SHIFT16), __expf(ov.y - SHIFT16)));       \
            ep[2 * mt + 1] = __builtin_bit_cast(uint32,                       \
                pkrtz(__expf(ov.z - SHIFT16), __expf(ov.w - SHIFT16)));       \
        }                                                                     \
        cstep<FW, (U) & 3>(v_, nv, head, D, ep, Af, Lacc, rs, saK);           \
    } } while (0)

template <bool FW>
__device__ __forceinline__ void chain(const float* __restrict__ obs,
                                      const float* __restrict__ trans,
                                      float* __restrict__ ws, int cg, int sg)
{
    const int l = threadIdx.x & 63;
    const int q = l >> 4, n = l & 15;
    const int NITd = FW ? 2048 : 2047;
    const int nv   = (!FW && sg == NSEG - 1) ? (WSEG + LSEG - 1) : (WSEG + LSEG);
    const bool head = (sg == 0);
    const bool mid  = (sg == NSEG - 1);
    const int itb = (sg - 1) * LSEG;     // global it = itb + v
    // per-lane byte base: chain row (cg*16+n), q-quarter offset
    const u64 lbase = (u64)(const char*)obs
                    + ((u64)(cg * 16 + n) << 21)   // * 4096 t * 512 B
                    + (u64)(q << 4);

    // exp(A) A-fragments. fwd: D = eA^T*W -> A[m][k]=eA[k][m]; bwd: A[m][k]=eA[m][k]
    h8 Af[8][4];
    #pragma unroll
    for (int mt = 0; mt < 8; ++mt)
        #pragma unroll
        for (int kc = 0; kc < 4; ++kc) {
            h8 a;
            #pragma unroll
            for (int j = 0; j < 8; ++j) {
                const int k = kc * 32 + q * 8 + j;
                const int m = mt * 16 + n;
                a[j] = (half_t)__expf(FW ? trans[k * 128 + m] : trans[m * 128 + k]);
            }
            Af[mt][kc] = a;
        }

    uint4 G[4][8];                        // 4-tile register ring (static idx)
    ISSUE8(0, itb + 0);                   // prologue: tiles 0,1 in flight
    ISSUE8(1, itb + 1);

    f4 D[8];
    #pragma unroll
    for (int mt = 0; mt < 8; ++mt) D[mt] = (f4){1.f, 1.f, 1.f, 1.f};
    float Lacc = 0.f, rs = 1.f, saK = 1.f;

    #pragma unroll 1
    for (int tt = 0; tt < (WSEG + LSEG) / 8; ++tt) {
        SUBSTEP(0); SUBSTEP(1); SUBSTEP(2); SUBSTEP(3);
        SUBSTEP(4); SUBSTEP(5); SUBSTEP(6); SUBSTEP(7);
    }
    WAIT_VM(0);                           // drain leftover prefetches

    // epilogue: midpoint waves store the state tile; all waves store scalars
    const float swK = chain_sum(D);
    if (mid) {
        float* Xo = ws + (FW ? WX : WQ) + ((cg * 16 + n) << 7);
        #pragma unroll
        for (int mt = 0; mt < 8; ++mt)
            *(f4*)&Xo[mt * 16 + q * 4] = D[mt];
    }
    // scalars: ws[WSC + (cg*2+dir)*768 + {0:L, 256:sw, 512:sa} + sg*16 + n]
    float* sc = ws + WSC + (cg * 2 + (FW ? 0 : 1)) * 768;
    if (q == 0) {
        sc[sg * 16 + n]       = Lacc;
        sc[256 + sg * 16 + n] = swK;
        sc[512 + sg * 16 + n] = head ? 1.0f : saK;
    }
}

__global__ __launch_bounds__(64, 1)
void crf_mfma(const float* __restrict__ obs, const float* __restrict__ trans,
              float* __restrict__ ws)
{
    const int bid = blockIdx.x;           // 128 blocks: dir*64 + cg*16 + sg
    const int r = bid & 63;
    const int cg = r >> 4, sg = r & 15;
    if (bid < 64) chain<true >(obs, trans, ws, cg, sg);
    else          chain<false>(obs, trans, ws, cg, sg);
}

// Z = sum_s X[s]*eo_2048[s]*Q[s]; out = -(log Z + corrections + 4096*SHIFT16)
// corrections: per dir: sum_s L_s + sum_{s>=1} [log sw_{s-1} - log sa_s]
__global__ __launch_bounds__(64)
void crf_comb(const float* __restrict__ obs, const float* __restrict__ ws,
              float* __restrict__ out)
{
    const int b = blockIdx.x, l = threadIdx.x;
    const int cg = b >> 4, n = b & 15;
    const int s0 = 2 * l;
    const float2 o = *(const float2*)&obs[((((size_t)b << 12) + 2048) << 7) + s0];
    const float e0 = __expf(o.x - SHIFT16), e1 = __expf(o.y - SHIFT16);
    float v = ws[WX + b * 128 + s0] * e0 * ws[WQ + b * 128 + s0]
            + ws[WX + b * 128 + s0 + 1] * e1 * ws[WQ + b * 128 + s0 + 1];
    v += __shfl_xor(v, 1);  v += __shfl_xor(v, 2);  v += __shfl_xor(v, 4);
    v += __shfl_xor(v, 8);  v += __shfl_xor(v, 16); v += __shfl_xor(v, 32);
    if (l == 0) {
        float corr = 0.f;
        #pragma unroll
        for (int dir = 0; dir < 2; ++dir) {
            const float* sc = ws + WSC + (cg * 2 + dir) * 768;
            #pragma unroll
            for (int s = 0; s < NSEG; ++s) corr += sc[s * 16 + n];
            #pragma unroll
            for (int s = 1; s < NSEG; ++s)
                corr += __logf(sc[256 + (s - 1) * 16 + n])
                      - __logf(sc[512 + s * 16 + n]);
        }
        out[b] = -(__logf(v) + corr + 4096.0f * SHIFT16);
    }
}

// ======================= FALLBACK (ws too small) ============================

typedef _Float16 h2f __attribute__((ext_vector_type(2)));
#define FTILE 16
#define FNTILE 128

#if __has_builtin(__builtin_amdgcn_fdot2)
#define FDOT2(p, e, acc) __builtin_amdgcn_fdot2((p), (e), (acc), false)
#else
#define FDOT2(p, e, acc) fmaf((float)(p).x, (float)(e).x, fmaf((float)(p).y, (float)(e).y, (acc)))
#endif

__device__ __forceinline__ h2f u2h(uint32 u) { return __builtin_bit_cast(h2f, u); }
__device__ __forceinline__ uint32 f2h(float f) {
    return (uint32)__builtin_bit_cast(unsigned short, (half_t)f);
}

#define FSTEP(N0, APPLY, MEAS)  do {                                                \
    const int row_ = fw ? ((N0) & (FTILE - 1)) : ((FTILE - 1) - ((N0) & (FTILE - 1))); \
    const float2 o2_ = *(const float2*)&obsL[(((N0) >> 4) & 1) * (FTILE * 128) + (row_ << 7) + (l << 1)]; \
    float e0_ = __expf(o2_.x - SHIFT8);                                             \
    float e1_ = __expf(o2_.y - SHIFT8);                                             \
    if (APPLY) { e0_ *= rsf; e1_ *= rsf; }                                          \
    float w0_, w1_;                                                                 \
    if (fw) { w0_ = pv0; w1_ = pv1; } else { w0_ = pv0 * e0_; w1_ = pv1 * e1_; }    \
    Pl[l] = (f2h(w1_) << 16) | f2h(w0_);                                            \
    float a0_=0.f,a1_=0.f,a2_=0.f,a3_=0.f,b0_=0.f,b1_=0.f,b2_=0.f,b3_=0.f;          \
    _Pragma("unroll")                                                               \
    for (int c_ = 0; c_ < 16; ++c_) {                                               \
        const uint4 q_ = ((const uint4*)Pl)[c_];                                    \
        const h2f p0_ = u2h(q_.x), p1_ = u2h(q_.y), p2_ = u2h(q_.z), p3_ = u2h(q_.w); \
        a0_ = FDOT2(p0_, eA[4*c_+0], a0_);                                          \
        a1_ = FDOT2(p1_, eA[4*c_+1], a1_);                                          \
        a2_ = FDOT2(p2_, eA[4*c_+2], a2_);                                          \
        a3_ = FDOT2(p3_, eA[4*c_+3], a3_);                                          \
        b0_ = FDOT2(p0_, eB[4*c_+0], b0_);                                          \
        b1_ = FDOT2(p1_, eB[4*c_+1], b1_);                                          \
        b2_ = FDOT2(p2_, eB[4*c_+2], b2_);                                          \
        b3_ = FDOT2(p3_, eB[4*c_+3], b3_);                                          \
    }                                                                               \
    const float s0_ = (a0_ + a1_) + (a2_ + a3_);                                    \
    const float s1_ = (b0_ + b1_) + (b2_ + b3_);                                    \
    if (fw) { pv0 = s0_ * e0_; pv1 = s1_ * e1_; } else { pv0 = s0_; pv1 = s1_; }    \
    if (MEAS) {                                                                     \
        float m_ = fmaxf(pv0, pv1);                                                 \
        m_ = fmaxf(m_, __shfl_xor(m_, 1));                                          \
        m_ = fmaxf(m_, __shfl_xor(m_, 2));                                          \
        m_ = fmaxf(m_, __shfl_xor(m_, 4));                                          \
        m_ = fmaxf(m_, __shfl_xor(m_, 8));                                          \
        m_ = fmaxf(m_, __shfl_xor(m_, 16));                                         \
        m_ = fmaxf(m_, __shfl_xor(m_, 32));                                         \
        rsf = __builtin_amdgcn_rcpf(m_);                                            \
        Lacc += __logf(m_);                                                         \
    }                                                                               \
} while (0)

#define FLOADR(TK) do {                                                             \
    const float4* g_ = (const float4*)(obsB + (size_t)(fw ? (TK) * (FTILE * 128)    \
                                      : (4096 - FTILE * ((TK) + 1)) * 128));        \
    r0 = g_[l];       r1 = g_[l + 64];  r2 = g_[l + 128]; r3 = g_[l + 192];         \
    r4 = g_[l + 256]; r5 = g_[l + 320]; r6 = g_[l + 384]; r7 = g_[l + 448];         \
} while (0)

#define FSTORER(TK) do {                                                            \
    float4* s_ = (float4*)&obsL[((TK) & 1) * (FTILE * 128)];                        \
    s_[l] = r0;       s_[l + 64] = r1;  s_[l + 128] = r2; s_[l + 192] = r3;         \
    s_[l + 256] = r4; s_[l + 320] = r5; s_[l + 384] = r6; s_[l + 448] = r7;         \
} while (0)

__global__ __launch_bounds__(64, 1)
void crf_half_fb(const float* __restrict__ obs, const float* __restrict__ trans,
                 float* __restrict__ ws)
{
    __shared__ __align__(16) uint32 Pl[64];
    __shared__ __align__(16) float obsL[2 * FTILE * 128];

    const int l  = threadIdx.x;
    const bool fw = blockIdx.x < 64;
    const int b  = fw ? blockIdx.x : blockIdx.x - 64;
    const float* obsB = obs + (size_t)b * 4096 * 128;

    h2f eA[64], eB[64];
    if (fw) {
        const int c0 = 2 * l;
        #pragma unroll
        for (int k = 0; k < 64; ++k) {
            h2f ta, tb;
            ta.x = (half_t)__expf(trans[(2*k    ) * 128 + c0]);
            ta.y = (half_t)__expf(trans[(2*k + 1) * 128 + c0]);
            tb.x = (half_t)__expf(trans[(2*k    ) * 128 + c0 + 1]);
            tb.y = (half_t)__expf(trans[(2*k + 1) * 128 + c0 + 1]);
            eA[k] = ta; eB[k] = tb;
        }
    } else {
        const int ro0 = (2 * l) * 128, ro1 = (2 * l + 1) * 128;
        #pragma unroll
        for (int k = 0; k < 64; ++k) {
            h2f ta, tb;
            ta.x = (half_t)__expf(trans[ro0 + 2*k]);
            ta.y = (half_t)__expf(trans[ro0 + 2*k + 1]);
            tb.x = (half_t)__expf(trans[ro1 + 2*k]);
            tb.y = (half_t)__expf(trans[ro1 + 2*k + 1]);
            eA[k] = ta; eB[k] = tb;
        }
    }

    float4 r0, r1, r2, r3, r4, r5, r6, r7;
    FLOADR(0);
    FSTORER(0);
    FLOADR(1);

    float rsf = 1.f, Lacc = 0.f, pv0, pv1;

    if (fw) {
        const float2 o2 = *(const float2*)&obsL[l << 1];
        pv0 = __expf(o2.x - SHIFT8);
        pv1 = __expf(o2.y - SHIFT8);
    } else {
        pv0 = 1.f; pv1 = 1.f;
        FSTEP(0, false, false);
    }

    for (int tile = 0; tile < FNTILE; ++tile) {
        if (tile > 0) {
            FSTORER(tile);
            if (tile < FNTILE - 1) FLOADR(tile + 1);
        }
        const int nb = tile << 4;
        #pragma unroll 1
        for (int g = 0; g < 4; ++g) {
            const int n0 = nb + (g << 2);
            if (n0 > 0) FSTEP(n0, true, false);
            FSTEP(n0 + 1, false, false);
            FSTEP(n0 + 2, false, false);
            if (n0 + 3 != 2047) FSTEP(n0 + 3, false, true);
            else                FSTEP(n0 + 3, false, false);
        }
    }

    if (fw) {
        ws[b * 128 + 2*l]     = pv0;
        ws[b * 128 + 2*l + 1] = pv1;
        if (l == 0) ws[16384 + b] = Lacc;
    } else {
        ws[8192 + b * 128 + 2*l]     = pv0;
        ws[8192 + b * 128 + 2*l + 1] = pv1;
        if (l == 0) ws[16448 + b] = Lacc;
    }
}

__global__ __launch_bounds__(64)
void crf_comb_fb(const float* __restrict__ ws, float* __restrict__ out)
{
    const int b = blockIdx.x, l = threadIdx.x;
    float s = ws[b * 128 + 2*l] * ws[8192 + b * 128 + 2*l]
            + ws[b * 128 + 2*l + 1] * ws[8192 + b * 128 + 2*l + 1];
    s += __shfl_xor(s, 1);  s += __shfl_xor(s, 2);  s += __shfl_xor(s, 4);
    s += __shfl_xor(s, 8);  s += __shfl_xor(s, 16); s += __shfl_xor(s, 32);
    if (l == 0)
        out[b] = -(__logf(s) + ws[16384 + b] + ws[16448 + b] + 4096.0f * SHIFT8);
}

// ============================================================================

extern "C" void kernel_launch(void* const* d_in, const int* in_sizes, int n_in,
                              void* d_out, int out_size, void* d_ws, size_t ws_size,
                              hipStream_t stream) {
    (void)in_sizes; (void)n_in; (void)out_size;
    const float* obs   = (const float*)d_in[0];   // [64, 4096, 128] fp32
    const float* trans = (const float*)d_in[1];   // [128, 128] fp32
    float* out = (float*)d_out;                   // [64] fp32
    float* ws  = (float*)d_ws;

    if (ws_size >= (size_t)FAST_WS_BYTES) {
        hipLaunchKernelGGL(crf_mfma, dim3(128), dim3(64), 0, stream, obs, trans, ws);
        hipLaunchKernelGGL(crf_comb, dim3(64),  dim3(64), 0, stream, obs, ws, out);
    } else {
        hipLaunchKernelGGL(crf_half_fb, dim3(128), dim3(64), 0, stream, obs, trans, ws);
        hipLaunchKernelGGL(crf_comb_fb, dim3(64),  dim3(64), 0, stream, ws, out);
    }
}

// Round 6
// 294.437 us; speedup vs baseline: 3.7205x; 1.1401x over previous
//
#include <hip/hip_runtime.h>

typedef _Float16 half_t;
typedef _Float16 h8 __attribute__((ext_vector_type(8)));
typedef _Float16 h2 __attribute__((ext_vector_type(2)));
typedef float f4 __attribute__((ext_vector_type(4)));
typedef unsigned int uint32;
typedef unsigned long long u64;
typedef unsigned int u2v __attribute__((ext_vector_type(2)));

#define SHIFT16 2.772588722239781f    // log(16), fast path
#define SHIFT8  2.0794415416798357f   // log(8), fallback path
// ws float offsets: X[64][128] | Q[64][128] | scalars[4cg][2dir][3][32seg][16n]
#define WX 0
#define WQ 8192
#define WSC 16384
#define FAST_WS_BYTES 114688u         // 28672 floats

#define WAIT_VM(n)   asm volatile("s_waitcnt vmcnt(" #n ")" ::: "memory")

// inline-asm global load: program-order issue, counted vmcnt, can't be sunk
#define GL4(dst, addr, OFFSTR) \
    asm volatile("global_load_dwordx4 %0, %1, off offset:" OFFSTR \
                 : "=v"(dst) : "v"(addr))

__device__ __forceinline__ h2 pkrtz(float a, float b) {
    return __builtin_bit_cast(h2, __builtin_amdgcn_cvt_pkrtz(a, b));
}

// (a,b) <- ([a.lanes0-31 | b.lanes0-31], [a.lanes32-63 | b.lanes32-63])
__device__ __forceinline__ void swap32(uint32& a, uint32& b) {
#if __has_builtin(__builtin_amdgcn_permlane32_swap)
    u2v r = __builtin_amdgcn_permlane32_swap(a, b, false, false);
    a = r.x; b = r.y;
#else
    const uint32 pa = (uint32)__shfl_xor((int)a, 32);
    const uint32 pb = (uint32)__shfl_xor((int)b, 32);
    const bool hi = (threadIdx.x & 32) != 0;
    const uint32 na = hi ? pb : a;
    const uint32 nb = hi ? b : pa;
    a = na; b = nb;
#endif
}
// per 32-lane half: (a,b) <- ([a0-15|b0-15|a32-47|b32-47], [a16-31|b16-31|a48-63|b48-63])
__device__ __forceinline__ void swap16(uint32& a, uint32& b) {
#if __has_builtin(__builtin_amdgcn_permlane16_swap)
    u2v r = __builtin_amdgcn_permlane16_swap(a, b, false, false);
    a = r.x; b = r.y;
#else
    const uint32 sa = (uint32)__builtin_amdgcn_ds_swizzle((int)a, 0x401F);
    const uint32 sb = (uint32)__builtin_amdgcn_ds_swizzle((int)b, 0x401F);
    const bool m = (threadIdx.x & 16) != 0;
    const uint32 na = m ? sb : a;
    const uint32 nb = m ? b : sa;
    a = na; b = nb;
#endif
}

// pure-VALU wave max over lane bits 4 and 5
__device__ __forceinline__ float wavemax_hi(float M) {
    uint32 ma = __builtin_bit_cast(uint32, M), mb = ma;
    swap16(ma, mb);
    M = fmaxf(__builtin_bit_cast(float, ma), __builtin_bit_cast(float, mb));
    ma = __builtin_bit_cast(uint32, M); mb = ma;
    swap32(ma, mb);
    return fmaxf(__builtin_bit_cast(float, ma), __builtin_bit_cast(float, mb));
}

// pure-VALU wave sum over lane bits 4 and 5 (sums the 4 q-lanes of a chain)
__device__ __forceinline__ float wavesum_hi(float S) {
    uint32 a = __builtin_bit_cast(uint32, S), b = a;
    swap16(a, b);
    S = __builtin_bit_cast(float, a) + __builtin_bit_cast(float, b);
    a = __builtin_bit_cast(uint32, S); b = a;
    swap32(a, b);
    return __builtin_bit_cast(float, a) + __builtin_bit_cast(float, b);
}

// per-chain sum of the 128-state vector held in D (across mt, elems, q-lanes)
__device__ __forceinline__ float chain_sum(const f4 (&D)[8]) {
    f4 s4 = (D[0] + D[1]) + (D[2] + D[3]);
    s4 = s4 + ((D[4] + D[5]) + (D[6] + D[7]));
    float S = (s4.x + s4.y) + (s4.z + s4.w);
    return wavesum_hi(S);
}

// ============================ FAST PATH =====================================

#define TE(N) (FW ? (N) : (4095 - (N)))
#define WSEG 96      // warmup substeps (128 validated in R4; 96 = wide margin)
#define LSEG 64      // main substeps per segment
#define NSEG 32      // 2048 / LSEG

template <bool FW, int ST>
__device__ __forceinline__ void cstep(int v, int nv, bool head,
                                      f4 (&D)[8], const uint32 (&ep)[16],
                                      const h8 (&Af)[8][4],
                                      float& Lacc, float& rs, float& saK)
{
    const f4 Z = {0.f, 0.f, 0.f, 0.f};

    if (ST == 0) {                       // apply pending renorm (fp32, exact)
        #pragma unroll
        for (int mt = 0; mt < 8; ++mt) D[mt] = D[mt] * rs;
        if (v == WSEG) {                 // segment boundary: end of warmup
            if (head) {                  // exact chain head: true init
                #pragma unroll
                for (int mt = 0; mt < 8; ++mt) D[mt] = (f4){1.f, 1.f, 1.f, 1.f};
            } else {
                saK = chain_sum(D);      // warm-start direction sum (per chain)
            }
            Lacc = 0.f;                  // discard warmup scale bookkeeping
        }
    }
    if (ST == 3) {
        if (v != nv - 1) {               // measure; pure VALU (permlane max)
            f4 m01 = __builtin_elementwise_max(D[0], D[1]);
            f4 m23 = __builtin_elementwise_max(D[2], D[3]);
            f4 m45 = __builtin_elementwise_max(D[4], D[5]);
            f4 m67 = __builtin_elementwise_max(D[6], D[7]);
            f4 ma = __builtin_elementwise_max(
                        __builtin_elementwise_max(m01, m23),
                        __builtin_elementwise_max(m45, m67));
            float M = fmaxf(fmaxf(ma.x, ma.y), fmaxf(ma.z, ma.w));
            M = wavemax_hi(M);
            Lacc += __logf(M);
            rs = __builtin_amdgcn_rcpf(M);
        }
    }

    // pack W = fp16(D) * eo  (register-resident)
    uint32 Wx[8], Wy[8];
    #pragma unroll
    for (int mt = 0; mt < 8; ++mt) {
        h2 w0 = pkrtz(D[mt].x, D[mt].y) * __builtin_bit_cast(h2, ep[2 * mt]);
        h2 w1 = pkrtz(D[mt].z, D[mt].w) * __builtin_bit_cast(h2, ep[2 * mt + 1]);
        Wx[mt] = __builtin_bit_cast(uint32, w0);
        Wy[mt] = __builtin_bit_cast(uint32, w1);
    }

    // cross-lane permute D-layout -> B-fragment layout (no LDS)
    h8 Bf[4];
    #pragma unroll
    for (int kc = 0; kc < 4; ++kc) {
        uint32 x0 = Wx[2 * kc], x1 = Wx[2 * kc + 1];
        uint32 y0 = Wy[2 * kc], y1 = Wy[2 * kc + 1];
        swap32(x0, x1); swap16(x0, x1);   // x0=d0, x1=d2
        swap32(y0, y1); swap16(y0, y1);   // y0=d1, y1=d3
        uint4 bv; bv.x = x0; bv.y = y0; bv.z = x1; bv.w = y1;
        Bf[kc] = __builtin_bit_cast(h8, bv);
    }

    // 32 MFMAs: 8 independent mt chains of depth 4
    #pragma unroll
    for (int mt = 0; mt < 8; ++mt) {
        f4 acc = Z;
        acc = __builtin_amdgcn_mfma_f32_16x16x32_f16(Af[mt][0], Bf[0], acc, 0, 0, 0);
        acc = __builtin_amdgcn_mfma_f32_16x16x32_f16(Af[mt][1], Bf[1], acc, 0, 0, 0);
        acc = __builtin_amdgcn_mfma_f32_16x16x32_f16(Af[mt][2], Bf[2], acc, 0, 0, 0);
        acc = __builtin_amdgcn_mfma_f32_16x16x32_f16(Af[mt][3], Bf[3], acc, 0, 0, 0);
        D[mt] = acc;
    }
}

// Issue 8 gather-loads of lane's 32 states (chain n, timestep ip) into G[B].
// Lane l=q*16+n reads float4 at state offset mt*16+q*4 -> ep[2mt],ep[2mt+1].
#define ISSUE8(B, IPE) do {                                                   \
    int ip_ = (IPE);                                                          \
    ip_ = ip_ < 0 ? 0 : (ip_ > NITd - 1 ? NITd - 1 : ip_);                    \
    const u64 a_ = lbase + ((u64)TE(ip_) << 9);                               \
    GL4(G[B][0], a_, "0");   GL4(G[B][1], a_, "64");                          \
    GL4(G[B][2], a_, "128"); GL4(G[B][3], a_, "192");                         \
    GL4(G[B][4], a_, "256"); GL4(G[B][5], a_, "320");                         \
    GL4(G[B][6], a_, "384"); GL4(G[B][7], a_, "448");                         \
} while (0)

// One substep: issue tile v+2 (depth-2 prefetch, counted vmcnt), wait for
// tile v (vmcnt(16) = 2 tiles x 8 loads still in flight), exp+pack, compute.
#define SUBSTEP(U)  do {                                                      \
    const int v_ = tt * 8 + (U);                                              \
    if (v_ < nv) {                                                            \
        ISSUE8(((U) + 2) & 3, itb + v_ + 2);                                  \
        WAIT_VM(16);                     /* tile v landed in G[U&3] */        \
        __builtin_amdgcn_sched_barrier(0);                                    \
        uint32 ep[16];                                                        \
        _Pragma("unroll")                                                     \
        for (int mt = 0; mt < 8; ++mt) {                                      \
            const f4 ov = __builtin_bit_cast(f4, G[(U) & 3][mt]);             \
            ep[2 * mt] = __builtin_bit_cast(uint32,                           \
                pkrtz(__expf(ov.x - SHIFT16), __expf(ov.y - SHIFT16)));       \
            ep[2 * mt + 1] = __builtin_bit_cast(uint32,                       \
                pkrtz(__expf(ov.z - SHIFT16), __expf(ov.w - SHIFT16)));       \
        }                                                                     \
        cstep<FW, (U) & 3>(v_, nv, head, D, ep, Af, Lacc, rs, saK);           \
    } } while (0)

template <bool FW>
__device__ __forceinline__ void chain(const float* __restrict__ obs,
                                      const float* __restrict__ trans,
                                      float* __restrict__ ws, int cg, int sg)
{
    const int l = threadIdx.x & 63;
    const int q = l >> 4, n = l & 15;
    const int NITd = FW ? 2048 : 2047;
    const int nv   = (!FW && sg == NSEG - 1) ? (WSEG + LSEG - 1) : (WSEG + LSEG);
    const bool head = (sg == 0);
    const bool last = (sg == NSEG - 1);
    const int itb = sg * LSEG - WSEG;    // global it = itb + v
    // per-lane byte base: chain row (cg*16+n), q-quarter offset
    const u64 lbase = (u64)(const char*)obs
                    + ((u64)(cg * 16 + n) << 21)   // * 4096 t * 512 B
                    + (u64)(q << 4);

    // exp(A) A-fragments. fwd: D = eA^T*W -> A[m][k]=eA[k][m]; bwd: A[m][k]=eA[m][k]
    h8 Af[8][4];
    #pragma unroll
    for (int mt = 0; mt < 8; ++mt)
        #pragma unroll
        for (int kc = 0; kc < 4; ++kc) {
            h8 a;
            #pragma unroll
            for (int j = 0; j < 8; ++j) {
                const int k = kc * 32 + q * 8 + j;
                const int m = mt * 16 + n;
                a[j] = (half_t)__expf(FW ? trans[k * 128 + m] : trans[m * 128 + k]);
            }
            Af[mt][kc] = a;
        }

    uint4 G[4][8];                        // 4-tile register ring (static idx)
    ISSUE8(0, itb + 0);                   // prologue: tiles 0,1 in flight
    ISSUE8(1, itb + 1);

    f4 D[8];
    #pragma unroll
    for (int mt = 0; mt < 8; ++mt) D[mt] = (f4){1.f, 1.f, 1.f, 1.f};
    float Lacc = 0.f, rs = 1.f, saK = 1.f;

    #pragma unroll 1
    for (int tt = 0; tt < (WSEG + LSEG) / 8; ++tt) {
        SUBSTEP(0); SUBSTEP(1); SUBSTEP(2); SUBSTEP(3);
        SUBSTEP(4); SUBSTEP(5); SUBSTEP(6); SUBSTEP(7);
    }
    WAIT_VM(0);                           // drain leftover prefetches

    // epilogue: last-segment waves store the chain-end state; all store scalars
    const float swK = chain_sum(D);
    if (last) {
        float* Xo = ws + (FW ? WX : WQ) + ((cg * 16 + n) << 7);
        #pragma unroll
        for (int mt = 0; mt < 8; ++mt)
            *(f4*)&Xo[mt * 16 + q * 4] = D[mt];
    }
    // scalars: ws[WSC + (cg*2+dir)*1536 + {0:L, 512:sw, 1024:sa} + sg*16 + n]
    float* sc = ws + WSC + (cg * 2 + (FW ? 0 : 1)) * 1536;
    if (q == 0) {
        sc[sg * 16 + n]        = Lacc;
        sc[512 + sg * 16 + n]  = swK;
        sc[1024 + sg * 16 + n] = head ? 1.0f : saK;
    }
}

__global__ __launch_bounds__(64, 1)
void crf_mfma(const float* __restrict__ obs, const float* __restrict__ trans,
              float* __restrict__ ws)
{
    const int bid = blockIdx.x;           // 256 blocks: dir*128 + cg*32 + sg
    const int r = bid & 127;
    const int cg = r >> 5, sg = r & 31;
    if (bid < 128) chain<true >(obs, trans, ws, cg, sg);
    else           chain<false>(obs, trans, ws, cg, sg);
}

// Z = sum_s X[s]*eo_2048[s]*Q[s]; out = -(log Z + corrections + 4096*SHIFT16)
// corrections: per dir: sum_s L_s + sum_{s>=1} [log sw_{s-1} - log sa_s]
__global__ __launch_bounds__(64)
void crf_comb(const float* __restrict__ obs, const float* __restrict__ ws,
              float* __restrict__ out)
{
    const int b = blockIdx.x, l = threadIdx.x;
    const int cg = b >> 4, n = b & 15;
    const int s0 = 2 * l;
    const float2 o = *(const float2*)&obs[((((size_t)b << 12) + 2048) << 7) + s0];
    const float e0 = __expf(o.x - SHIFT16), e1 = __expf(o.y - SHIFT16);
    float v = ws[WX + b * 128 + s0] * e0 * ws[WQ + b * 128 + s0]
            + ws[WX + b * 128 + s0 + 1] * e1 * ws[WQ + b * 128 + s0 + 1];
    v += __shfl_xor(v, 1);  v += __shfl_xor(v, 2);  v += __shfl_xor(v, 4);
    v += __shfl_xor(v, 8);  v += __shfl_xor(v, 16); v += __shfl_xor(v, 32);
    if (l == 0) {
        float corr = 0.f;
        #pragma unroll
        for (int dir = 0; dir < 2; ++dir) {
            const float* sc = ws + WSC + (cg * 2 + dir) * 1536;
            #pragma unroll
            for (int s = 0; s < NSEG; ++s) corr += sc[s * 16 + n];
            #pragma unroll
            for (int s = 1; s < NSEG; ++s)
                corr += __logf(sc[512 + (s - 1) * 16 + n])
                      - __logf(sc[1024 + s * 16 + n]);
        }
        out[b] = -(__logf(v) + corr + 4096.0f * SHIFT16);
    }
}

// ======================= FALLBACK (ws too small) ============================

typedef _Float16 h2f __attribute__((ext_vector_type(2)));
#define FTILE 16
#define FNTILE 128

#if __has_builtin(__builtin_amdgcn_fdot2)
#define FDOT2(p, e, acc) __builtin_amdgcn_fdot2((p), (e), (acc), false)
#else
#define FDOT2(p, e, acc) fmaf((float)(p).x, (float)(e).x, fmaf((float)(p).y, (float)(e).y, (acc)))
#endif

__device__ __forceinline__ h2f u2h(uint32 u) { return __builtin_bit_cast(h2f, u); }
__device__ __forceinline__ uint32 f2h(float f) {
    return (uint32)__builtin_bit_cast(unsigned short, (half_t)f);
}

#define FSTEP(N0, APPLY, MEAS)  do {                                                \
    const int row_ = fw ? ((N0) & (FTILE - 1)) : ((FTILE - 1) - ((N0) & (FTILE - 1))); \
    const float2 o2_ = *(const float2*)&obsL[(((N0) >> 4) & 1) * (FTILE * 128) + (row_ << 7) + (l << 1)]; \
    float e0_ = __expf(o2_.x - SHIFT8);                                             \
    float e1_ = __expf(o2_.y - SHIFT8);                                             \
    if (APPLY) { e0_ *= rsf; e1_ *= rsf; }                                          \
    float w0_, w1_;                                                                 \
    if (fw) { w0_ = pv0; w1_ = pv1; } else { w0_ = pv0 * e0_; w1_ = pv1 * e1_; }    \
    Pl[l] = (f2h(w1_) << 16) | f2h(w0_);                                            \
    float a0_=0.f,a1_=0.f,a2_=0.f,a3_=0.f,b0_=0.f,b1_=0.f,b2_=0.f,b3_=0.f;          \
    _Pragma("unroll")                                                               \
    for (int c_ = 0; c_ < 16; ++c_) {                                               \
        const uint4 q_ = ((const uint4*)Pl)[c_];                                    \
        const h2f p0_ = u2h(q_.x), p1_ = u2h(q_.y), p2_ = u2h(q_.z), p3_ = u2h(q_.w); \
        a0_ = FDOT2(p0_, eA[4*c_+0], a0_);                                          \
        a1_ = FDOT2(p1_, eA[4*c_+1], a1_);                                          \
        a2_ = FDOT2(p2_, eA[4*c_+2], a2_);                                          \
        a3_ = FDOT2(p3_, eA[4*c_+3], a3_);                                          \
        b0_ = FDOT2(p0_, eB[4*c_+0], b0_);                                          \
        b1_ = FDOT2(p1_, eB[4*c_+1], b1_);                                          \
        b2_ = FDOT2(p2_, eB[4*c_+2], b2_);                                          \
        b3_ = FDOT2(p3_, eB[4*c_+3], b3_);                                          \
    }                                                                               \
    const float s0_ = (a0_ + a1_) + (a2_ + a3_);                                    \
    const float s1_ = (b0_ + b1_) + (b2_ + b3_);                                    \
    if (fw) { pv0 = s0_ * e0_; pv1 = s1_ * e1_; } else { pv0 = s0_; pv1 = s1_; }    \
    if (MEAS) {                                                                     \
        float m_ = fmaxf(pv0, pv1);                                                 \
        m_ = fmaxf(m_, __shfl_xor(m_, 1));                                          \
        m_ = fmaxf(m_, __shfl_xor(m_, 2));                                          \
        m_ = fmaxf(m_, __shfl_xor(m_, 4));                                          \
        m_ = fmaxf(m_, __shfl_xor(m_, 8));                                          \
        m_ = fmaxf(m_, __shfl_xor(m_, 16));                                         \
        m_ = fmaxf(m_, __shfl_xor(m_, 32));                                         \
        rsf = __builtin_amdgcn_rcpf(m_);                                            \
        Lacc += __logf(m_);                                                         \
    }                                                                               \
} while (0)

#define FLOADR(TK) do {                                                             \
    const float4* g_ = (const float4*)(obsB + (size_t)(fw ? (TK) * (FTILE * 128)    \
                                      : (4096 - FTILE * ((TK) + 1)) * 128));        \
    r0 = g_[l];       r1 = g_[l + 64];  r2 = g_[l + 128]; r3 = g_[l + 192];         \
    r4 = g_[l + 256]; r5 = g_[l + 320]; r6 = g_[l + 384]; r7 = g_[l + 448];         \
} while (0)

#define FSTORER(TK) do {                                                            \
    float4* s_ = (float4*)&obsL[((TK) & 1) * (FTILE * 128)];                        \
    s_[l] = r0;       s_[l + 64] = r1;  s_[l + 128] = r2; s_[l + 192] = r3;         \
    s_[l + 256] = r4; s_[l + 320] = r5; s_[l + 384] = r6; s_[l + 448] = r7;         \
} while (0)

__global__ __launch_bounds__(64, 1)
void crf_half_fb(const float* __restrict__ obs, const float* __restrict__ trans,
                 float* __restrict__ ws)
{
    __shared__ __align__(16) uint32 Pl[64];
    __shared__ __align__(16) float obsL[2 * FTILE * 128];

    const int l  = threadIdx.x;
    const bool fw = blockIdx.x < 64;
    const int b  = fw ? blockIdx.x : blockIdx.x - 64;
    const float* obsB = obs + (size_t)b * 4096 * 128;

    h2f eA[64], eB[64];
    if (fw) {
        const int c0 = 2 * l;
        #pragma unroll
        for (int k = 0; k < 64; ++k) {
            h2f ta, tb;
            ta.x = (half_t)__expf(trans[(2*k    ) * 128 + c0]);
            ta.y = (half_t)__expf(trans[(2*k + 1) * 128 + c0]);
            tb.x = (half_t)__expf(trans[(2*k    ) * 128 + c0 + 1]);
            tb.y = (half_t)__expf(trans[(2*k + 1) * 128 + c0 + 1]);
            eA[k] = ta; eB[k] = tb;
        }
    } else {
        const int ro0 = (2 * l) * 128, ro1 = (2 * l + 1) * 128;
        #pragma unroll
        for (int k = 0; k < 64; ++k) {
            h2f ta, tb;
            ta.x = (half_t)__expf(trans[ro0 + 2*k]);
            ta.y = (half_t)__expf(trans[ro0 + 2*k + 1]);
            tb.x = (half_t)__expf(trans[ro1 + 2*k]);
            tb.y = (half_t)__expf(trans[ro1 + 2*k + 1]);
            eA[k] = ta; eB[k] = tb;
        }
    }

    float4 r0, r1, r2, r3, r4, r5, r6, r7;
    FLOADR(0);
    FSTORER(0);
    FLOADR(1);

    float rsf = 1.f, Lacc = 0.f, pv0, pv1;

    if (fw) {
        const float2 o2 = *(const float2*)&obsL[l << 1];
        pv0 = __expf(o2.x - SHIFT8);
        pv1 = __expf(o2.y - SHIFT8);
    } else {
        pv0 = 1.f; pv1 = 1.f;
        FSTEP(0, false, false);
    }

    for (int tile = 0; tile < FNTILE; ++tile) {
        if (tile > 0) {
            FSTORER(tile);
            if (tile < FNTILE - 1) FLOADR(tile + 1);
        }
        const int nb = tile << 4;
        #pragma unroll 1
        for (int g = 0; g < 4; ++g) {
            const int n0 = nb + (g << 2);
            if (n0 > 0) FSTEP(n0, true, false);
            FSTEP(n0 + 1, false, false);
            FSTEP(n0 + 2, false, false);
            if (n0 + 3 != 2047) FSTEP(n0 + 3, false, true);
            else                FSTEP(n0 + 3, false, false);
        }
    }

    if (fw) {
        ws[b * 128 + 2*l]     = pv0;
        ws[b * 128 + 2*l + 1] = pv1;
        if (l == 0) ws[16384 + b] = Lacc;
    } else {
        ws[8192 + b * 128 + 2*l]     = pv0;
        ws[8192 + b * 128 + 2*l + 1] = pv1;
        if (l == 0) ws[16448 + b] = Lacc;
    }
}

__global__ __launch_bounds__(64)
void crf_comb_fb(const float* __restrict__ ws, float* __restrict__ out)
{
    const int b = blockIdx.x, l = threadIdx.x;
    float s = ws[b * 128 + 2*l] * ws[8192 + b * 128 + 2*l]
            + ws[b * 128 + 2*l + 1] * ws[8192 + b * 128 + 2*l + 1];
    s += __shfl_xor(s, 1);  s += __shfl_xor(s, 2);  s += __shfl_xor(s, 4);
    s += __shfl_xor(s, 8);  s += __shfl_xor(s, 16); s += __shfl_xor(s, 32);
    if (l == 0)
        out[b] = -(__logf(s) + ws[16384 + b] + ws[16448 + b] + 4096.0f * SHIFT8);
}

// ============================================================================

extern "C" void kernel_launch(void* const* d_in, const int* in_sizes, int n_in,
                              void* d_out, int out_size, void* d_ws, size_t ws_size,
                              hipStream_t stream) {
    (void)in_sizes; (void)n_in; (void)out_size;
    const float* obs   = (const float*)d_in[0];   // [64, 4096, 128] fp32
    const float* trans = (const float*)d_in[1];   // [128, 128] fp32
    float* out = (float*)d_out;                   // [64] fp32
    float* ws  = (float*)d_ws;

    if (ws_size >= (size_t)FAST_WS_BYTES) {
        hipLaunchKernelGGL(crf_mfma, dim3(256), dim3(64), 0, stream, obs, trans, ws);
        hipLaunchKernelGGL(crf_comb, dim3(64),  dim3(64), 0, stream, obs, ws, out);
    } else {
        hipLaunchKernelGGL(crf_half_fb, dim3(128), dim3(64), 0, stream, obs, trans, ws);
        hipLaunchKernelGGL(crf_comb_fb, dim3(64),  dim3(64), 0, stream, ws, out);
    }
}

// Round 8
// 251.282 us; speedup vs baseline: 4.3595x; 1.1717x over previous
//
#include <hip/hip_runtime.h>

typedef _Float16 half_t;
typedef _Float16 h8 __attribute__((ext_vector_type(8)));
typedef _Float16 h2 __attribute__((ext_vector_type(2)));
typedef float f4 __attribute__((ext_vector_type(4)));
typedef unsigned int uint32;
typedef unsigned long long u64;
typedef unsigned int u2v __attribute__((ext_vector_type(2)));

#define SHIFT16 2.772588722239781f    // log(16), fast path
#define SHIFT8  2.0794415416798357f   // log(8), fallback path
// ws float offsets: X[64][128] | Q[64][128] | scalars[4cg][2dir][3][64seg][16n]
#define WX 0
#define WQ 8192
#define WSC 16384
#define FAST_WS_BYTES 163840u         // 40960 floats

#define WAIT_VM(n)   asm volatile("s_waitcnt vmcnt(" #n ")" ::: "memory")

// inline-asm global load: program-order issue, counted vmcnt, can't be sunk
#define GL4(dst, addr, OFFSTR) \
    asm volatile("global_load_dwordx4 %0, %1, off offset:" OFFSTR \
                 : "=v"(dst) : "v"(addr))

__device__ __forceinline__ h2 pkrtz(float a, float b) {
    return __builtin_bit_cast(h2, __builtin_amdgcn_cvt_pkrtz(a, b));
}

// (a,b) <- ([a.lanes0-31 | b.lanes0-31], [a.lanes32-63 | b.lanes32-63])
__device__ __forceinline__ void swap32(uint32& a, uint32& b) {
#if __has_builtin(__builtin_amdgcn_permlane32_swap)
    u2v r = __builtin_amdgcn_permlane32_swap(a, b, false, false);
    a = r.x; b = r.y;
#else
    const uint32 pa = (uint32)__shfl_xor((int)a, 32);
    const uint32 pb = (uint32)__shfl_xor((int)b, 32);
    const bool hi = (threadIdx.x & 32) != 0;
    const uint32 na = hi ? pb : a;
    const uint32 nb = hi ? b : pa;
    a = na; b = nb;
#endif
}
// per 32-lane half: (a,b) <- ([a0-15|b0-15|a32-47|b32-47], [a16-31|b16-31|a48-63|b48-63])
__device__ __forceinline__ void swap16(uint32& a, uint32& b) {
#if __has_builtin(__builtin_amdgcn_permlane16_swap)
    u2v r = __builtin_amdgcn_permlane16_swap(a, b, false, false);
    a = r.x; b = r.y;
#else
    const uint32 sa = (uint32)__builtin_amdgcn_ds_swizzle((int)a, 0x401F);
    const uint32 sb = (uint32)__builtin_amdgcn_ds_swizzle((int)b, 0x401F);
    const bool m = (threadIdx.x & 16) != 0;
    const uint32 na = m ? sb : a;
    const uint32 nb = m ? b : sa;
    a = na; b = nb;
#endif
}

// pure-VALU wave max over lane bits 4 and 5
__device__ __forceinline__ float wavemax_hi(float M) {
    uint32 ma = __builtin_bit_cast(uint32, M), mb = ma;
    swap16(ma, mb);
    M = fmaxf(__builtin_bit_cast(float, ma), __builtin_bit_cast(float, mb));
    ma = __builtin_bit_cast(uint32, M); mb = ma;
    swap32(ma, mb);
    return fmaxf(__builtin_bit_cast(float, ma), __builtin_bit_cast(float, mb));
}

// pure-VALU wave sum over lane bits 4 and 5 (sums the 4 q-lanes of a chain)
__device__ __forceinline__ float wavesum_hi(float S) {
    uint32 a = __builtin_bit_cast(uint32, S), b = a;
    swap16(a, b);
    S = __builtin_bit_cast(float, a) + __builtin_bit_cast(float, b);
    a = __builtin_bit_cast(uint32, S); b = a;
    swap32(a, b);
    return __builtin_bit_cast(float, a) + __builtin_bit_cast(float, b);
}

// per-chain sum of the 128-state vector held in D (across mt, elems, q-lanes)
__device__ __forceinline__ float chain_sum(const f4 (&D)[8]) {
    f4 s4 = (D[0] + D[1]) + (D[2] + D[3]);
    s4 = s4 + ((D[4] + D[5]) + (D[6] + D[7]));
    float S = (s4.x + s4.y) + (s4.z + s4.w);
    return wavesum_hi(S);
}

// ============================ FAST PATH =====================================

#define TE(N) (FW ? (N) : (4095 - (N)))
#define WSEG 32      // warmup substeps (96 validated R6; contraction ~c^32)
#define LSEG 32      // main substeps per segment
#define NSEG 64      // 2048 / LSEG

template <bool FW, int ST>
__device__ __forceinline__ void cstep(int v, int nv, bool head,
                                      f4 (&D)[8], const uint32 (&ep)[16],
                                      const h8 (&Af)[8][4],
                                      float& Lacc, float& rs, float& saK)
{
    const f4 Z = {0.f, 0.f, 0.f, 0.f};

    if (ST == 0) {                       // apply pending renorm (fp32, exact)
        #pragma unroll
        for (int mt = 0; mt < 8; ++mt) D[mt] = D[mt] * rs;
        if (v == WSEG) {                 // segment boundary: end of warmup
            if (head) {                  // exact chain head: true init
                #pragma unroll
                for (int mt = 0; mt < 8; ++mt) D[mt] = (f4){1.f, 1.f, 1.f, 1.f};
            } else {
                saK = chain_sum(D);      // warm-start direction sum (per chain)
            }
            Lacc = 0.f;                  // discard warmup scale bookkeeping
        }
    }
    if (ST == 3) {
        if (v != nv - 1) {               // measure; pure VALU (permlane max)
            f4 m01 = __builtin_elementwise_max(D[0], D[1]);
            f4 m23 = __builtin_elementwise_max(D[2], D[3]);
            f4 m45 = __builtin_elementwise_max(D[4], D[5]);
            f4 m67 = __builtin_elementwise_max(D[6], D[7]);
            f4 ma = __builtin_elementwise_max(
                        __builtin_elementwise_max(m01, m23),
                        __builtin_elementwise_max(m45, m67));
            float M = fmaxf(fmaxf(ma.x, ma.y), fmaxf(ma.z, ma.w));
            M = wavemax_hi(M);
            Lacc += __logf(M);
            rs = __builtin_amdgcn_rcpf(M);
        }
    }

    // pack W = fp16(D) * eo  (register-resident)
    uint32 Wx[8], Wy[8];
    #pragma unroll
    for (int mt = 0; mt < 8; ++mt) {
        h2 w0 = pkrtz(D[mt].x, D[mt].y) * __builtin_bit_cast(h2, ep[2 * mt]);
        h2 w1 = pkrtz(D[mt].z, D[mt].w) * __builtin_bit_cast(h2, ep[2 * mt + 1]);
        Wx[mt] = __builtin_bit_cast(uint32, w0);
        Wy[mt] = __builtin_bit_cast(uint32, w1);
    }

    // cross-lane permute D-layout -> B-fragment layout (no LDS)
    h8 Bf[4];
    #pragma unroll
    for (int kc = 0; kc < 4; ++kc) {
        uint32 x0 = Wx[2 * kc], x1 = Wx[2 * kc + 1];
        uint32 y0 = Wy[2 * kc], y1 = Wy[2 * kc + 1];
        swap32(x0, x1); swap16(x0, x1);   // x0=d0, x1=d2
        swap32(y0, y1); swap16(y0, y1);   // y0=d1, y1=d3
        uint4 bv; bv.x = x0; bv.y = y0; bv.z = x1; bv.w = y1;
        Bf[kc] = __builtin_bit_cast(h8, bv);
    }

    // 32 MFMAs: 8 independent mt chains of depth 4
    #pragma unroll
    for (int mt = 0; mt < 8; ++mt) {
        f4 acc = Z;
        acc = __builtin_amdgcn_mfma_f32_16x16x32_f16(Af[mt][0], Bf[0], acc, 0, 0, 0);
        acc = __builtin_amdgcn_mfma_f32_16x16x32_f16(Af[mt][1], Bf[1], acc, 0, 0, 0);
        acc = __builtin_amdgcn_mfma_f32_16x16x32_f16(Af[mt][2], Bf[2], acc, 0, 0, 0);
        acc = __builtin_amdgcn_mfma_f32_16x16x32_f16(Af[mt][3], Bf[3], acc, 0, 0, 0);
        D[mt] = acc;
    }
}

// Issue 8 gather-loads of lane's 32 states (chain n, timestep ip) into G[B].
// Lane l=q*16+n reads float4 at state offset mt*16+q*4 -> ep[2mt],ep[2mt+1].
#define ISSUE8(B, IPE) do {                                                   \
    int ip_ = (IPE);                                                          \
    ip_ = ip_ < 0 ? 0 : (ip_ > NITd - 1 ? NITd - 1 : ip_);                    \
    const u64 a_ = lbase + ((u64)TE(ip_) << 9);                               \
    GL4(G[B][0], a_, "0");   GL4(G[B][1], a_, "64");                          \
    GL4(G[B][2], a_, "128"); GL4(G[B][3], a_, "192");                         \
    GL4(G[B][4], a_, "256"); GL4(G[B][5], a_, "320");                         \
    GL4(G[B][6], a_, "384"); GL4(G[B][7], a_, "448");                         \
} while (0)

// One substep: issue tile v+2 (depth-2 prefetch, counted vmcnt), wait for
// tile v (vmcnt(16) = 2 tiles x 8 loads still in flight), exp+pack, compute.
#define SUBSTEP(U)  do {                                                      \
    const int v_ = tt * 8 + (U);                                              \
    if (v_ < nv) {                                                            \
        ISSUE8(((U) + 2) & 3, itb + v_ + 2);                                  \
        WAIT_VM(16);                     /* tile v landed in G[U&3] */        \
        __builtin_amdgcn_sched_barrier(0);                                    \
        uint32 ep[16];                                                        \
        _Pragma("unroll")                                                     \
        for (int mt = 0; mt < 8; ++mt) {                                      \
            const f4 ov = __builtin_bit_cast(f4, G[(U) & 3][mt]);             \
            ep[2 * mt] = __builtin_bit_cast(uint32,                           \
                pkrtz(__expf(ov.x - SHIFT16), __expf(ov.y - SHIFT16)));       \
            ep[2 * mt + 1] = __builtin_bit_cast(uint32,                       \
                pkrtz(__expf(ov.z - SHIFT16), __expf(ov.w - SHIFT16)));       \
        }                                                                     \
        cstep<FW, (U) & 3>(v_, nv, head, D, ep, Af, Lacc, rs, saK);           \
    } } while (0)

template <bool FW>
__device__ __forceinline__ void chain(const float* __restrict__ obs,
                                      const float* __restrict__ trans,
                                      float* __restrict__ ws, int cg, int sg)
{
    const int l = threadIdx.x & 63;
    const int q = l >> 4, n = l & 15;
    const int NITd = FW ? 2048 : 2047;
    const int nv   = (!FW && sg == NSEG - 1) ? (WSEG + LSEG - 1) : (WSEG + LSEG);
    const bool head = (sg == 0);
    const bool last = (sg == NSEG - 1);
    const int itb = sg * LSEG - WSEG;    // global it = itb + v
    // per-lane byte base: chain row (cg*16+n), q-quarter offset
    const u64 lbase = (u64)(const char*)obs
                    + ((u64)(cg * 16 + n) << 21)   // * 4096 t * 512 B
                    + (u64)(q << 4);

    // exp(A) A-fragments. fwd: D = eA^T*W -> A[m][k]=eA[k][m]; bwd: A[m][k]=eA[m][k]
    h8 Af[8][4];
    #pragma unroll
    for (int mt = 0; mt < 8; ++mt)
        #pragma unroll
        for (int kc = 0; kc < 4; ++kc) {
            h8 a;
            #pragma unroll
            for (int j = 0; j < 8; ++j) {
                const int k = kc * 32 + q * 8 + j;
                const int m = mt * 16 + n;
                a[j] = (half_t)__expf(FW ? trans[k * 128 + m] : trans[m * 128 + k]);
            }
            Af[mt][kc] = a;
        }

    uint4 G[4][8];                        // 4-tile register ring (static idx)
    ISSUE8(0, itb + 0);                   // prologue: tiles 0,1 in flight
    ISSUE8(1, itb + 1);

    f4 D[8];
    #pragma unroll
    for (int mt = 0; mt < 8; ++mt) D[mt] = (f4){1.f, 1.f, 1.f, 1.f};
    float Lacc = 0.f, rs = 1.f, saK = 1.f;

    #pragma unroll 1
    for (int tt = 0; tt < (WSEG + LSEG) / 8; ++tt) {
        SUBSTEP(0); SUBSTEP(1); SUBSTEP(2); SUBSTEP(3);
        SUBSTEP(4); SUBSTEP(5); SUBSTEP(6); SUBSTEP(7);
    }
    WAIT_VM(0);                           // drain leftover prefetches

    // epilogue: last-segment waves store the chain-end state; all store scalars
    const float swK = chain_sum(D);
    if (last) {
        float* Xo = ws + (FW ? WX : WQ) + ((cg * 16 + n) << 7);
        #pragma unroll
        for (int mt = 0; mt < 8; ++mt)
            *(f4*)&Xo[mt * 16 + q * 4] = D[mt];
    }
    // scalars: ws[WSC + (cg*2+dir)*3072 + {0:L, 1024:sw, 2048:sa} + sg*16 + n]
    float* sc = ws + WSC + (cg * 2 + (FW ? 0 : 1)) * 3072;
    if (q == 0) {
        sc[sg * 16 + n]        = Lacc;
        sc[1024 + sg * 16 + n] = swK;
        sc[2048 + sg * 16 + n] = head ? 1.0f : saK;
    }
}

__global__ __launch_bounds__(64, 1)
void crf_mfma(const float* __restrict__ obs, const float* __restrict__ trans,
              float* __restrict__ ws)
{
    const int bid = blockIdx.x;           // 512 blocks: dir*256 + cg*64 + sg
    const int r = bid & 255;
    const int cg = r >> 6, sg = r & 63;
    if (bid < 256) chain<true >(obs, trans, ws, cg, sg);
    else           chain<false>(obs, trans, ws, cg, sg);
}

// Z = sum_s X[s]*eo_2048[s]*Q[s]; out = -(log Z + corrections + 4096*SHIFT16)
// corrections: per dir: sum_s L_s + sum_{s>=1} [log sw_{s-1} - log sa_s].
// Lane l handles segment s=l (NSEG=64 == wave width); shuffle-reduced.
__global__ __launch_bounds__(64)
void crf_comb(const float* __restrict__ obs, const float* __restrict__ ws,
              float* __restrict__ out)
{
    const int b = blockIdx.x, l = threadIdx.x;
    const int cg = b >> 4, n = b & 15;
    const int s0 = 2 * l;
    const float2 o = *(const float2*)&obs[((((size_t)b << 12) + 2048) << 7) + s0];
    const float e0 = __expf(o.x - SHIFT16), e1 = __expf(o.y - SHIFT16);
    float v = ws[WX + b * 128 + s0] * e0 * ws[WQ + b * 128 + s0]
            + ws[WX + b * 128 + s0 + 1] * e1 * ws[WQ + b * 128 + s0 + 1];

    float corr = 0.f;                     // per-lane segment partials
    #pragma unroll
    for (int dir = 0; dir < 2; ++dir) {
        const float* sc = ws + WSC + (cg * 2 + dir) * 3072;
        float p = sc[l * 16 + n];
        if (l >= 1)
            p += __logf(sc[1024 + (l - 1) * 16 + n])
               - __logf(sc[2048 + l * 16 + n]);
        corr += p;
    }

    v += __shfl_xor(v, 1);  v += __shfl_xor(v, 2);  v += __shfl_xor(v, 4);
    v += __shfl_xor(v, 8);  v += __shfl_xor(v, 16); v += __shfl_xor(v, 32);
    corr += __shfl_xor(corr, 1);  corr += __shfl_xor(corr, 2);
    corr += __shfl_xor(corr, 4);  corr += __shfl_xor(corr, 8);
    corr += __shfl_xor(corr, 16); corr += __shfl_xor(corr, 32);
    if (l == 0)
        out[b] = -(__logf(v) + corr + 4096.0f * SHIFT16);
}

// ======================= FALLBACK (ws too small) ============================

typedef _Float16 h2f __attribute__((ext_vector_type(2)));
#define FTILE 16
#define FNTILE 128

#if __has_builtin(__builtin_amdgcn_fdot2)
#define FDOT2(p, e, acc) __builtin_amdgcn_fdot2((p), (e), (acc), false)
#else
#define FDOT2(p, e, acc) fmaf((float)(p).x, (float)(e).x, fmaf((float)(p).y, (float)(e).y, (acc)))
#endif

__device__ __forceinline__ h2f u2h(uint32 u) { return __builtin_bit_cast(h2f, u); }
__device__ __forceinline__ uint32 f2h(float f) {
    return (uint32)__builtin_bit_cast(unsigned short, (half_t)f);
}

#define FSTEP(N0, APPLY, MEAS)  do {                                                \
    const int row_ = fw ? ((N0) & (FTILE - 1)) : ((FTILE - 1) - ((N0) & (FTILE - 1))); \
    const float2 o2_ = *(const float2*)&obsL[(((N0) >> 4) & 1) * (FTILE * 128) + (row_ << 7) + (l << 1)]; \
    float e0_ = __expf(o2_.x - SHIFT8);                                             \
    float e1_ = __expf(o2_.y - SHIFT8);                                             \
    if (APPLY) { e0_ *= rsf; e1_ *= rsf; }                                          \
    float w0_, w1_;                                                                 \
    if (fw) { w0_ = pv0; w1_ = pv1; } else { w0_ = pv0 * e0_; w1_ = pv1 * e1_; }    \
    Pl[l] = (f2h(w1_) << 16) | f2h(w0_);                                            \
    float a0_=0.f,a1_=0.f,a2_=0.f,a3_=0.f,b0_=0.f,b1_=0.f,b2_=0.f,b3_=0.f;          \
    _Pragma("unroll")                                                               \
    for (int c_ = 0; c_ < 16; ++c_) {                                               \
        const uint4 q_ = ((const uint4*)Pl)[c_];                                    \
        const h2f p0_ = u2h(q_.x), p1_ = u2h(q_.y), p2_ = u2h(q_.z), p3_ = u2h(q_.w); \
        a0_ = FDOT2(p0_, eA[4*c_+0], a0_);                                          \
        a1_ = FDOT2(p1_, eA[4*c_+1], a1_);                                          \
        a2_ = FDOT2(p2_, eA[4*c_+2], a2_);                                          \
        a3_ = FDOT2(p3_, eA[4*c_+3], a3_);                                          \
        b0_ = FDOT2(p0_, eB[4*c_+0], b0_);                                          \
        b1_ = FDOT2(p1_, eB[4*c_+1], b1_);                                          \
        b2_ = FDOT2(p2_, eB[4*c_+2], b2_);                                          \
        b3_ = FDOT2(p3_, eB[4*c_+3], b3_);                                          \
    }                                                                               \
    const float s0_ = (a0_ + a1_) + (a2_ + a3_);                                    \
    const float s1_ = (b0_ + b1_) + (b2_ + b3_);                                    \
    if (fw) { pv0 = s0_ * e0_; pv1 = s1_ * e1_; } else { pv0 = s0_; pv1 = s1_; }    \
    if (MEAS) {                                                                     \
        float m_ = fmaxf(pv0, pv1);                                                 \
        m_ = fmaxf(m_, __shfl_xor(m_, 1));                                          \
        m_ = fmaxf(m_, __shfl_xor(m_, 2));                                          \
        m_ = fmaxf(m_, __shfl_xor(m_, 4));                                          \
        m_ = fmaxf(m_, __shfl_xor(m_, 8));                                          \
        m_ = fmaxf(m_, __shfl_xor(m_, 16));                                         \
        m_ = fmaxf(m_, __shfl_xor(m_, 32));                                         \
        rsf = __builtin_amdgcn_rcpf(m_);                                            \
        Lacc += __logf(m_);                                                         \
    }                                                                               \
} while (0)

#define FLOADR(TK) do {                                                             \
    const float4* g_ = (const float4*)(obsB + (size_t)(fw ? (TK) * (FTILE * 128)    \
                                      : (4096 - FTILE * ((TK) + 1)) * 128));        \
    r0 = g_[l];       r1 = g_[l + 64];  r2 = g_[l + 128]; r3 = g_[l + 192];         \
    r4 = g_[l + 256]; r5 = g_[l + 320]; r6 = g_[l + 384]; r7 = g_[l + 448];         \
} while (0)

#define FSTORER(TK) do {                                                            \
    float4* s_ = (float4*)&obsL[((TK) & 1) * (FTILE * 128)];                        \
    s_[l] = r0;       s_[l + 64] = r1;  s_[l + 128] = r2; s_[l + 192] = r3;         \
    s_[l + 256] = r4; s_[l + 320] = r5; s_[l + 384] = r6; s_[l + 448] = r7;         \
} while (0)

__global__ __launch_bounds__(64, 1)
void crf_half_fb(const float* __restrict__ obs, const float* __restrict__ trans,
                 float* __restrict__ ws)
{
    __shared__ __align__(16) uint32 Pl[64];
    __shared__ __align__(16) float obsL[2 * FTILE * 128];

    const int l  = threadIdx.x;
    const bool fw = blockIdx.x < 64;
    const int b  = fw ? blockIdx.x : blockIdx.x - 64;
    const float* obsB = obs + (size_t)b * 4096 * 128;

    h2f eA[64], eB[64];
    if (fw) {
        const int c0 = 2 * l;
        #pragma unroll
        for (int k = 0; k < 64; ++k) {
            h2f ta, tb;
            ta.x = (half_t)__expf(trans[(2*k    ) * 128 + c0]);
            ta.y = (half_t)__expf(trans[(2*k + 1) * 128 + c0]);
            tb.x = (half_t)__expf(trans[(2*k    ) * 128 + c0 + 1]);
            tb.y = (half_t)__expf(trans[(2*k + 1) * 128 + c0 + 1]);
            eA[k] = ta; eB[k] = tb;
        }
    } else {
        const int ro0 = (2 * l) * 128, ro1 = (2 * l + 1) * 128;
        #pragma unroll
        for (int k = 0; k < 64; ++k) {
            h2f ta, tb;
            ta.x = (half_t)__expf(trans[ro0 + 2*k]);
            ta.y = (half_t)__expf(trans[ro0 + 2*k + 1]);
            tb.x = (half_t)__expf(trans[ro1 + 2*k]);
            tb.y = (half_t)__expf(trans[ro1 + 2*k + 1]);
            eA[k] = ta; eB[k] = tb;
        }
    }

    float4 r0, r1, r2, r3, r4, r5, r6, r7;
    FLOADR(0);
    FSTORER(0);
    FLOADR(1);

    float rsf = 1.f, Lacc = 0.f, pv0, pv1;

    if (fw) {
        const float2 o2 = *(const float2*)&obsL[l << 1];
        pv0 = __expf(o2.x - SHIFT8);
        pv1 = __expf(o2.y - SHIFT8);
    } else {
        pv0 = 1.f; pv1 = 1.f;
        FSTEP(0, false, false);
    }

    for (int tile = 0; tile < FNTILE; ++tile) {
        if (tile > 0) {
            FSTORER(tile);
            if (tile < FNTILE - 1) FLOADR(tile + 1);
        }
        const int nb = tile << 4;
        #pragma unroll 1
        for (int g = 0; g < 4; ++g) {
            const int n0 = nb + (g << 2);
            if (n0 > 0) FSTEP(n0, true, false);
            FSTEP(n0 + 1, false, false);
            FSTEP(n0 + 2, false, false);
            if (n0 + 3 != 2047) FSTEP(n0 + 3, false, true);
            else                FSTEP(n0 + 3, false, false);
        }
    }

    if (fw) {
        ws[b * 128 + 2*l]     = pv0;
        ws[b * 128 + 2*l + 1] = pv1;
        if (l == 0) ws[16384 + b] = Lacc;
    } else {
        ws[8192 + b * 128 + 2*l]     = pv0;
        ws[8192 + b * 128 + 2*l + 1] = pv1;
        if (l == 0) ws[16448 + b] = Lacc;
    }
}

__global__ __launch_bounds__(64)
void crf_comb_fb(const float* __restrict__ ws, float* __restrict__ out)
{
    const int b = blockIdx.x, l = threadIdx.x;
    float s = ws[b * 128 + 2*l] * ws[8192 + b * 128 + 2*l]
            + ws[b * 128 + 2*l + 1] * ws[8192 + b * 128 + 2*l + 1];
    s += __shfl_xor(s, 1);  s += __shfl_xor(s, 2);  s += __shfl_xor(s, 4);
    s += __shfl_xor(s, 8);  s += __shfl_xor(s, 16); s += __shfl_xor(s, 32);
    if (l == 0)
        out[b] = -(__logf(s) + ws[16384 + b] + ws[16448 + b] + 4096.0f * SHIFT8);
}

// ============================================================================

extern "C" void kernel_launch(void* const* d_in, const int* in_sizes, int n_in,
                              void* d_out, int out_size, void* d_ws, size_t ws_size,
                              hipStream_t stream) {
    (void)in_sizes; (void)n_in; (void)out_size;
    const float* obs   = (const float*)d_in[0];   // [64, 4096, 128] fp32
    const float* trans = (const float*)d_in[1];   // [128, 128] fp32
    float* out = (float*)d_out;                   // [64] fp32
    float* ws  = (float*)d_ws;

    if (ws_size >= (size_t)FAST_WS_BYTES) {
        hipLaunchKernelGGL(crf_mfma, dim3(512), dim3(64), 0, stream, obs, trans, ws);
        hipLaunchKernelGGL(crf_comb, dim3(64),  dim3(64), 0, stream, obs, ws, out);
    } else {
        hipLaunchKernelGGL(crf_half_fb, dim3(128), dim3(64), 0, stream, obs, trans, ws);
        hipLaunchKernelGGL(crf_comb_fb, dim3(64),  dim3(64), 0, stream, ws, out);
    }
}

// Round 9
// 243.301 us; speedup vs baseline: 4.5025x; 1.0328x over previous
//
#include <hip/hip_runtime.h>

typedef _Float16 half_t;
typedef _Float16 h8 __attribute__((ext_vector_type(8)));
typedef _Float16 h2 __attribute__((ext_vector_type(2)));
typedef float f4 __attribute__((ext_vector_type(4)));
typedef unsigned int uint32;
typedef unsigned long long u64;
typedef unsigned int u2v __attribute__((ext_vector_type(2)));

#define SHIFT16 2.772588722239781f    // log(16), fast path
#define SHIFT8  2.0794415416798357f   // log(8), fallback path
// ws float offsets: X[64][128] | Q[64][128] | scalars[4cg][2dir][3][32seg][16n]
#define WX 0
#define WQ 8192
#define WSC 16384
#define FAST_WS_BYTES 114688u         // 28672 floats

#define WAIT_VM(n)   asm volatile("s_waitcnt vmcnt(" #n ")" ::: "memory")

// inline-asm global load: program-order issue, counted vmcnt, can't be sunk
#define GL4(dst, addr, OFFSTR) \
    asm volatile("global_load_dwordx4 %0, %1, off offset:" OFFSTR \
                 : "=v"(dst) : "v"(addr))

__device__ __forceinline__ h2 pkrtz(float a, float b) {
    return __builtin_bit_cast(h2, __builtin_amdgcn_cvt_pkrtz(a, b));
}

// (a,b) <- ([a.lanes0-31 | b.lanes0-31], [a.lanes32-63 | b.lanes32-63])
__device__ __forceinline__ void swap32(uint32& a, uint32& b) {
#if __has_builtin(__builtin_amdgcn_permlane32_swap)
    u2v r = __builtin_amdgcn_permlane32_swap(a, b, false, false);
    a = r.x; b = r.y;
#else
    const uint32 pa = (uint32)__shfl_xor((int)a, 32);
    const uint32 pb = (uint32)__shfl_xor((int)b, 32);
    const bool hi = (threadIdx.x & 32) != 0;
    const uint32 na = hi ? pb : a;
    const uint32 nb = hi ? b : pa;
    a = na; b = nb;
#endif
}
// per 32-lane half: (a,b) <- ([a0-15|b0-15|a32-47|b32-47], [a16-31|b16-31|a48-63|b48-63])
__device__ __forceinline__ void swap16(uint32& a, uint32& b) {
#if __has_builtin(__builtin_amdgcn_permlane16_swap)
    u2v r = __builtin_amdgcn_permlane16_swap(a, b, false, false);
    a = r.x; b = r.y;
#else
    const uint32 sa = (uint32)__builtin_amdgcn_ds_swizzle((int)a, 0x401F);
    const uint32 sb = (uint32)__builtin_amdgcn_ds_swizzle((int)b, 0x401F);
    const bool m = (threadIdx.x & 16) != 0;
    const uint32 na = m ? sb : a;
    const uint32 nb = m ? b : sa;
    a = na; b = nb;
#endif
}

// pure-VALU wave max over lane bits 4 and 5
__device__ __forceinline__ float wavemax_hi(float M) {
    uint32 ma = __builtin_bit_cast(uint32, M), mb = ma;
    swap16(ma, mb);
    M = fmaxf(__builtin_bit_cast(float, ma), __builtin_bit_cast(float, mb));
    ma = __builtin_bit_cast(uint32, M); mb = ma;
    swap32(ma, mb);
    return fmaxf(__builtin_bit_cast(float, ma), __builtin_bit_cast(float, mb));
}

// pure-VALU wave sum over lane bits 4 and 5 (sums the 4 q-lanes of a chain)
__device__ __forceinline__ float wavesum_hi(float S) {
    uint32 a = __builtin_bit_cast(uint32, S), b = a;
    swap16(a, b);
    S = __builtin_bit_cast(float, a) + __builtin_bit_cast(float, b);
    a = __builtin_bit_cast(uint32, S); b = a;
    swap32(a, b);
    return __builtin_bit_cast(float, a) + __builtin_bit_cast(float, b);
}

// per-chain sum of the 128-state vector held in D (across mt, elems, q-lanes)
__device__ __forceinline__ float chain_sum(const f4 (&D)[8]) {
    f4 s4 = (D[0] + D[1]) + (D[2] + D[3]);
    s4 = s4 + ((D[4] + D[5]) + (D[6] + D[7]));
    float S = (s4.x + s4.y) + (s4.z + s4.w);
    return wavesum_hi(S);
}

// ============================ FAST PATH =====================================

#define TE(N) (FW ? (N) : (4095 - (N)))
#define WSEG 32      // warmup substeps (validated R8)
#define LSEG 64      // main substeps per segment -> read multiplicity 1.5x
#define NSEG 32      // 2048 / LSEG

template <bool FW, int ST>
__device__ __forceinline__ void cstep(int v, int nv, bool head,
                                      f4 (&D)[8], const uint32 (&ep)[16],
                                      const h8 (&Af)[8][4],
                                      float& Lacc, float& rs, float& saK)
{
    const f4 Z = {0.f, 0.f, 0.f, 0.f};

    if (ST == 0) {                       // apply pending renorm (fp32, exact)
        #pragma unroll
        for (int mt = 0; mt < 8; ++mt) D[mt] = D[mt] * rs;
        if (v == WSEG) {                 // segment boundary: end of warmup
            if (head) {                  // exact chain head: true init
                #pragma unroll
                for (int mt = 0; mt < 8; ++mt) D[mt] = (f4){1.f, 1.f, 1.f, 1.f};
            } else {
                saK = chain_sum(D);      // warm-start direction sum (per chain)
            }
            Lacc = 0.f;                  // discard warmup scale bookkeeping
        }
    }
    if (ST == 3) {
        if (v != nv - 1) {               // measure; pure VALU (permlane max)
            f4 m01 = __builtin_elementwise_max(D[0], D[1]);
            f4 m23 = __builtin_elementwise_max(D[2], D[3]);
            f4 m45 = __builtin_elementwise_max(D[4], D[5]);
            f4 m67 = __builtin_elementwise_max(D[6], D[7]);
            f4 ma = __builtin_elementwise_max(
                        __builtin_elementwise_max(m01, m23),
                        __builtin_elementwise_max(m45, m67));
            float M = fmaxf(fmaxf(ma.x, ma.y), fmaxf(ma.z, ma.w));
            M = wavemax_hi(M);
            Lacc += __logf(M);
            rs = __builtin_amdgcn_rcpf(M);
        }
    }

    // pack W = fp16(D) * eo  (register-resident)
    uint32 Wx[8], Wy[8];
    #pragma unroll
    for (int mt = 0; mt < 8; ++mt) {
        h2 w0 = pkrtz(D[mt].x, D[mt].y) * __builtin_bit_cast(h2, ep[2 * mt]);
        h2 w1 = pkrtz(D[mt].z, D[mt].w) * __builtin_bit_cast(h2, ep[2 * mt + 1]);
        Wx[mt] = __builtin_bit_cast(uint32, w0);
        Wy[mt] = __builtin_bit_cast(uint32, w1);
    }

    // cross-lane permute D-layout -> B-fragment layout (no LDS)
    h8 Bf[4];
    #pragma unroll
    for (int kc = 0; kc < 4; ++kc) {
        uint32 x0 = Wx[2 * kc], x1 = Wx[2 * kc + 1];
        uint32 y0 = Wy[2 * kc], y1 = Wy[2 * kc + 1];
        swap32(x0, x1); swap16(x0, x1);   // x0=d0, x1=d2
        swap32(y0, y1); swap16(y0, y1);   // y0=d1, y1=d3
        uint4 bv; bv.x = x0; bv.y = y0; bv.z = x1; bv.w = y1;
        Bf[kc] = __builtin_bit_cast(h8, bv);
    }

    // 32 MFMAs: 8 independent mt chains of depth 4
    #pragma unroll
    for (int mt = 0; mt < 8; ++mt) {
        f4 acc = Z;
        acc = __builtin_amdgcn_mfma_f32_16x16x32_f16(Af[mt][0], Bf[0], acc, 0, 0, 0);
        acc = __builtin_amdgcn_mfma_f32_16x16x32_f16(Af[mt][1], Bf[1], acc, 0, 0, 0);
        acc = __builtin_amdgcn_mfma_f32_16x16x32_f16(Af[mt][2], Bf[2], acc, 0, 0, 0);
        acc = __builtin_amdgcn_mfma_f32_16x16x32_f16(Af[mt][3], Bf[3], acc, 0, 0, 0);
        D[mt] = acc;
    }
}

// Issue 8 gather-loads of lane's 32 states (chain n, timestep ip) into G[B].
// Lane l=q*16+n reads float4 at state offset mt*16+q*4 -> ep[2mt],ep[2mt+1].
#define ISSUE8(B, IPE) do {                                                   \
    int ip_ = (IPE);                                                          \
    ip_ = ip_ < 0 ? 0 : (ip_ > NITd - 1 ? NITd - 1 : ip_);                    \
    const u64 a_ = lbase + ((u64)TE(ip_) << 9);                               \
    GL4(G[B][0], a_, "0");   GL4(G[B][1], a_, "64");                          \
    GL4(G[B][2], a_, "128"); GL4(G[B][3], a_, "192");                         \
    GL4(G[B][4], a_, "256"); GL4(G[B][5], a_, "320");                         \
    GL4(G[B][6], a_, "384"); GL4(G[B][7], a_, "448");                        \
} while (0)

// One substep: issue tile v+3 (depth-3 prefetch, counted vmcnt), wait for
// tile v (vmcnt(24) = 3 tiles x 8 loads still in flight), exp+pack, compute.
#define SUBSTEP(U)  do {                                                      \
    const int v_ = tt * 8 + (U);                                              \
    if (v_ < nv) {                                                            \
        ISSUE8(((U) + 3) & 3, itb + v_ + 3);                                  \
        WAIT_VM(24);                     /* tile v landed in G[U&3] */        \
        __builtin_amdgcn_sched_barrier(0);                                    \
        uint32 ep[16];                                                        \
        _Pragma("unroll")                                                     \
        for (int mt = 0; mt < 8; ++mt) {                                      \
            const f4 ov = __builtin_bit_cast(f4, G[(U) & 3][mt]);             \
            ep[2 * mt] = __builtin_bit_cast(uint32,                           \
                pkrtz(__expf(ov.x - SHIFT16), __expf(ov.y - SHIFT16)));       \
            ep[2 * mt + 1] = __builtin_bit_cast(uint32,                       \
                pkrtz(__expf(ov.z - SHIFT16), __expf(ov.w - SHIFT16)));       \
        }                                                                     \
        cstep<FW, (U) & 3>(v_, nv, head, D, ep, Af, Lacc, rs, saK);           \
    } } while (0)

template <bool FW>
__device__ __forceinline__ void chain(const float* __restrict__ obs,
                                      const float* __restrict__ trans,
                                      float* __restrict__ ws, int cg, int sg)
{
    const int l = threadIdx.x & 63;
    const int q = l >> 4, n = l & 15;
    const int NITd = FW ? 2048 : 2047;
    const int nv   = (!FW && sg == NSEG - 1) ? (WSEG + LSEG - 1) : (WSEG + LSEG);
    const bool head = (sg == 0);
    const bool last = (sg == NSEG - 1);
    const int itb = sg * LSEG - WSEG;    // global it = itb + v
    // per-lane byte base: chain row (cg*16+n), q-quarter offset
    const u64 lbase = (u64)(const char*)obs
                    + ((u64)(cg * 16 + n) << 21)   // * 4096 t * 512 B
                    + (u64)(q << 4);

    // exp(A) A-fragments. fwd: D = eA^T*W -> A[m][k]=eA[k][m]; bwd: A[m][k]=eA[m][k]
    h8 Af[8][4];
    #pragma unroll
    for (int mt = 0; mt < 8; ++mt)
        #pragma unroll
        for (int kc = 0; kc < 4; ++kc) {
            h8 a;
            #pragma unroll
            for (int j = 0; j < 8; ++j) {
                const int k = kc * 32 + q * 8 + j;
                const int m = mt * 16 + n;
                a[j] = (half_t)__expf(FW ? trans[k * 128 + m] : trans[m * 128 + k]);
            }
            Af[mt][kc] = a;
        }

    uint4 G[4][8];                        // 4-tile register ring (static idx)
    ISSUE8(0, itb + 0);                   // prologue: tiles 0,1,2 in flight
    ISSUE8(1, itb + 1);
    ISSUE8(2, itb + 2);

    f4 D[8];
    #pragma unroll
    for (int mt = 0; mt < 8; ++mt) D[mt] = (f4){1.f, 1.f, 1.f, 1.f};
    float Lacc = 0.f, rs = 1.f, saK = 1.f;

    #pragma unroll 1
    for (int tt = 0; tt < (WSEG + LSEG) / 8; ++tt) {
        SUBSTEP(0); SUBSTEP(1); SUBSTEP(2); SUBSTEP(3);
        SUBSTEP(4); SUBSTEP(5); SUBSTEP(6); SUBSTEP(7);
    }
    WAIT_VM(0);                           // drain leftover prefetches

    // epilogue: last-segment waves store the chain-end state; all store scalars
    const float swK = chain_sum(D);
    if (last) {
        float* Xo = ws + (FW ? WX : WQ) + ((cg * 16 + n) << 7);
        #pragma unroll
        for (int mt = 0; mt < 8; ++mt)
            *(f4*)&Xo[mt * 16 + q * 4] = D[mt];
    }
    // scalars: ws[WSC + (cg*2+dir)*1536 + {0:L, 512:sw, 1024:sa} + sg*16 + n]
    float* sc = ws + WSC + (cg * 2 + (FW ? 0 : 1)) * 1536;
    if (q == 0) {
        sc[sg * 16 + n]        = Lacc;
        sc[512 + sg * 16 + n]  = swK;
        sc[1024 + sg * 16 + n] = head ? 1.0f : saK;
    }
}

__global__ __launch_bounds__(64, 1)
void crf_mfma(const float* __restrict__ obs, const float* __restrict__ trans,
              float* __restrict__ ws)
{
    // XCD-locality decode: bid&7 selects the (dir,cg) group, so under
    // round-robin bid->XCD all 32 segments of one group share an XCD L2
    // (adjacent segments share 256KB: sg's main range == sg+1's warmup).
    const int bid = blockIdx.x;           // 256 blocks
    const int g = bid & 7;                // dir*4 + cg
    const int sg = bid >> 3;              // 0..31
    const int cg = g & 3;
    if (g < 4) chain<true >(obs, trans, ws, cg, sg);
    else       chain<false>(obs, trans, ws, cg, sg);
}

// Z = sum_s X[s]*eo_2048[s]*Q[s]; out = -(log Z + corrections + 4096*SHIFT16)
// corrections: per dir: sum_s L_s + sum_{s>=1} [log sw_{s-1} - log sa_s].
// Lane l handles (dir = l>>5, segment = l&31); shuffle-reduced over 64 lanes.
__global__ __launch_bounds__(64)
void crf_comb(const float* __restrict__ obs, const float* __restrict__ ws,
              float* __restrict__ out)
{
    const int b = blockIdx.x, l = threadIdx.x;
    const int cg = b >> 4, n = b & 15;
    const int s0 = 2 * l;
    const float2 o = *(const float2*)&obs[((((size_t)b << 12) + 2048) << 7) + s0];
    const float e0 = __expf(o.x - SHIFT16), e1 = __expf(o.y - SHIFT16);
    float v = ws[WX + b * 128 + s0] * e0 * ws[WQ + b * 128 + s0]
            + ws[WX + b * 128 + s0 + 1] * e1 * ws[WQ + b * 128 + s0 + 1];

    const int dir = l >> 5, s = l & 31;   // per-lane segment partial
    const float* sc = ws + WSC + (cg * 2 + dir) * 1536;
    float corr = sc[s * 16 + n];
    if (s >= 1)
        corr += __logf(sc[512 + (s - 1) * 16 + n])
              - __logf(sc[1024 + s * 16 + n]);

    v += __shfl_xor(v, 1);  v += __shfl_xor(v, 2);  v += __shfl_xor(v, 4);
    v += __shfl_xor(v, 8);  v += __shfl_xor(v, 16); v += __shfl_xor(v, 32);
    corr += __shfl_xor(corr, 1);  corr += __shfl_xor(corr, 2);
    corr += __shfl_xor(corr, 4);  corr += __shfl_xor(corr, 8);
    corr += __shfl_xor(corr, 16); corr += __shfl_xor(corr, 32);
    if (l == 0)
        out[b] = -(__logf(v) + corr + 4096.0f * SHIFT16);
}

// ======================= FALLBACK (ws too small) ============================

typedef _Float16 h2f __attribute__((ext_vector_type(2)));
#define FTILE 16
#define FNTILE 128

#if __has_builtin(__builtin_amdgcn_fdot2)
#define FDOT2(p, e, acc) __builtin_amdgcn_fdot2((p), (e), (acc), false)
#else
#define FDOT2(p, e, acc) fmaf((float)(p).x, (float)(e).x, fmaf((float)(p).y, (float)(e).y, (acc)))
#endif

__device__ __forceinline__ h2f u2h(uint32 u) { return __builtin_bit_cast(h2f, u); }
__device__ __forceinline__ uint32 f2h(float f) {
    return (uint32)__builtin_bit_cast(unsigned short, (half_t)f);
}

#define FSTEP(N0, APPLY, MEAS)  do {                                                \
    const int row_ = fw ? ((N0) & (FTILE - 1)) : ((FTILE - 1) - ((N0) & (FTILE - 1))); \
    const float2 o2_ = *(const float2*)&obsL[(((N0) >> 4) & 1) * (FTILE * 128) + (row_ << 7) + (l << 1)]; \
    float e0_ = __expf(o2_.x - SHIFT8);                                             \
    float e1_ = __expf(o2_.y - SHIFT8);                                             \
    if (APPLY) { e0_ *= rsf; e1_ *= rsf; }                                          \
    float w0_, w1_;                                                                 \
    if (fw) { w0_ = pv0; w1_ = pv1; } else { w0_ = pv0 * e0_; w1_ = pv1 * e1_; }    \
    Pl[l] = (f2h(w1_) << 16) | f2h(w0_);                                            \
    float a0_=0.f,a1_=0.f,a2_=0.f,a3_=0.f,b0_=0.f,b1_=0.f,b2_=0.f,b3_=0.f;          \
    _Pragma("unroll")                                                               \
    for (int c_ = 0; c_ < 16; ++c_) {                                               \
        const uint4 q_ = ((const uint4*)Pl)[c_];                                    \
        const h2f p0_ = u2h(q_.x), p1_ = u2h(q_.y), p2_ = u2h(q_.z), p3_ = u2h(q_.w); \
        a0_ = FDOT2(p0_, eA[4*c_+0], a0_);                                          \
        a1_ = FDOT2(p1_, eA[4*c_+1], a1_);                                          \
        a2_ = FDOT2(p2_, eA[4*c_+2], a2_);                                          \
        a3_ = FDOT2(p3_, eA[4*c_+3], a3_);                                          \
        b0_ = FDOT2(p0_, eB[4*c_+0], b0_);                                          \
        b1_ = FDOT2(p1_, eB[4*c_+1], b1_);                                          \
        b2_ = FDOT2(p2_, eB[4*c_+2], b2_);                                          \
        b3_ = FDOT2(p3_, eB[4*c_+3], b3_);                                          \
    }                                                                               \
    const float s0_ = (a0_ + a1_) + (a2_ + a3_);                                    \
    const float s1_ = (b0_ + b1_) + (b2_ + b3_);                                    \
    if (fw) { pv0 = s0_ * e0_; pv1 = s1_ * e1_; } else { pv0 = s0_; pv1 = s1_; }    \
    if (MEAS) {                                                                     \
        float m_ = fmaxf(pv0, pv1);                                                 \
        m_ = fmaxf(m_, __shfl_xor(m_, 1));                                          \
        m_ = fmaxf(m_, __shfl_xor(m_, 2));                                          \
        m_ = fmaxf(m_, __shfl_xor(m_, 4));                                          \
        m_ = fmaxf(m_, __shfl_xor(m_, 8));                                          \
        m_ = fmaxf(m_, __shfl_xor(m_, 16));                                         \
        m_ = fmaxf(m_, __shfl_xor(m_, 32));                                         \
        rsf = __builtin_amdgcn_rcpf(m_);                                            \
        Lacc += __logf(m_);                                                         \
    }                                                                               \
} while (0)

#define FLOADR(TK) do {                                                             \
    const float4* g_ = (const float4*)(obsB + (size_t)(fw ? (TK) * (FTILE * 128)    \
                                      : (4096 - FTILE * ((TK) + 1)) * 128));        \
    r0 = g_[l];       r1 = g_[l + 64];  r2 = g_[l + 128]; r3 = g_[l + 192];         \
    r4 = g_[l + 256]; r5 = g_[l + 320]; r6 = g_[l + 384]; r7 = g_[l + 448];         \
} while (0)

#define FSTORER(TK) do {                                                            \
    float4* s_ = (float4*)&obsL[((TK) & 1) * (FTILE * 128)];                        \
    s_[l] = r0;       s_[l + 64] = r1;  s_[l + 128] = r2; s_[l + 192] = r3;         \
    s_[l + 256] = r4; s_[l + 320] = r5; s_[l + 384] = r6; s_[l + 448] = r7;         \
} while (0)

__global__ __launch_bounds__(64, 1)
void crf_half_fb(const float* __restrict__ obs, const float* __restrict__ trans,
                 float* __restrict__ ws)
{
    __shared__ __align__(16) uint32 Pl[64];
    __shared__ __align__(16) float obsL[2 * FTILE * 128];

    const int l  = threadIdx.x;
    const bool fw = blockIdx.x < 64;
    const int b  = fw ? blockIdx.x : blockIdx.x - 64;
    const float* obsB = obs + (size_t)b * 4096 * 128;

    h2f eA[64], eB[64];
    if (fw) {
        const int c0 = 2 * l;
        #pragma unroll
        for (int k = 0; k < 64; ++k) {
            h2f ta, tb;
            ta.x = (half_t)__expf(trans[(2*k    ) * 128 + c0]);
            ta.y = (half_t)__expf(trans[(2*k + 1) * 128 + c0]);
            tb.x = (half_t)__expf(trans[(2*k    ) * 128 + c0 + 1]);
            tb.y = (half_t)__expf(trans[(2*k + 1) * 128 + c0 + 1]);
            eA[k] = ta; eB[k] = tb;
        }
    } else {
        const int ro0 = (2 * l) * 128, ro1 = (2 * l + 1) * 128;
        #pragma unroll
        for (int k = 0; k < 64; ++k) {
            h2f ta, tb;
            ta.x = (half_t)__expf(trans[ro0 + 2*k]);
            ta.y = (half_t)__expf(trans[ro0 + 2*k + 1]);
            tb.x = (half_t)__expf(trans[ro1 + 2*k]);
            tb.y = (half_t)__expf(trans[ro1 + 2*k + 1]);
            eA[k] = ta; eB[k] = tb;
        }
    }

    float4 r0, r1, r2, r3, r4, r5, r6, r7;
    FLOADR(0);
    FSTORER(0);
    FLOADR(1);

    float rsf = 1.f, Lacc = 0.f, pv0, pv1;

    if (fw) {
        const float2 o2 = *(const float2*)&obsL[l << 1];
        pv0 = __expf(o2.x - SHIFT8);
        pv1 = __expf(o2.y - SHIFT8);
    } else {
        pv0 = 1.f; pv1 = 1.f;
        FSTEP(0, false, false);
    }

    for (int tile = 0; tile < FNTILE; ++tile) {
        if (tile > 0) {
            FSTORER(tile);
            if (tile < FNTILE - 1) FLOADR(tile + 1);
        }
        const int nb = tile << 4;
        #pragma unroll 1
        for (int g = 0; g < 4; ++g) {
            const int n0 = nb + (g << 2);
            if (n0 > 0) FSTEP(n0, true, false);
            FSTEP(n0 + 1, false, false);
            FSTEP(n0 + 2, false, false);
            if (n0 + 3 != 2047) FSTEP(n0 + 3, false, true);
            else                FSTEP(n0 + 3, false, false);
        }
    }

    if (fw) {
        ws[b * 128 + 2*l]     = pv0;
        ws[b * 128 + 2*l + 1] = pv1;
        if (l == 0) ws[16384 + b] = Lacc;
    } else {
        ws[8192 + b * 128 + 2*l]     = pv0;
        ws[8192 + b * 128 + 2*l + 1] = pv1;
        if (l == 0) ws[16448 + b] = Lacc;
    }
}

__global__ __launch_bounds__(64)
void crf_comb_fb(const float* __restrict__ ws, float* __restrict__ out)
{
    const int b = blockIdx.x, l = threadIdx.x;
    float s = ws[b * 128 + 2*l] * ws[8192 + b * 128 + 2*l]
            + ws[b * 128 + 2*l + 1] * ws[8192 + b * 128 + 2*l + 1];
    s += __shfl_xor(s, 1);  s += __shfl_xor(s, 2);  s += __shfl_xor(s, 4);
    s += __shfl_xor(s, 8);  s += __shfl_xor(s, 16); s += __shfl_xor(s, 32);
    if (l == 0)
        out[b] = -(__logf(s) + ws[16384 + b] + ws[16448 + b] + 4096.0f * SHIFT8);
}

// ============================================================================

extern "C" void kernel_launch(void* const* d_in, const int* in_sizes, int n_in,
                              void* d_out, int out_size, void* d_ws, size_t ws_size,
                              hipStream_t stream) {
    (void)in_sizes; (void)n_in; (void)out_size;
    const float* obs   = (const float*)d_in[0];   // [64, 4096, 128] fp32
    const float* trans = (const float*)d_in[1];   // [128, 128] fp32
    float* out = (float*)d_out;                   // [64] fp32
    float* ws  = (float*)d_ws;

    if (ws_size >= (size_t)FAST_WS_BYTES) {
        hipLaunchKernelGGL(crf_mfma, dim3(256), dim3(64), 0, stream, obs, trans, ws);
        hipLaunchKernelGGL(crf_comb, dim3(64),  dim3(64), 0, stream, obs, ws, out);
    } else {
        hipLaunchKernelGGL(crf_half_fb, dim3(128), dim3(64), 0, stream, obs, trans, ws);
        hipLaunchKernelGGL(crf_comb_fb, dim3(64),  dim3(64), 0, stream, ws, out);
    }
}

// Round 10
// 241.654 us; speedup vs baseline: 4.5332x; 1.0068x over previous
//
#include <hip/hip_runtime.h>

typedef _Float16 half_t;
typedef _Float16 h8 __attribute__((ext_vector_type(8)));
typedef _Float16 h2 __attribute__((ext_vector_type(2)));
typedef float f4 __attribute__((ext_vector_type(4)));
typedef unsigned int uint32;
typedef unsigned long long u64;
typedef unsigned int u2v __attribute__((ext_vector_type(2)));

#define SHIFT16 2.772588722239781f    // log(16), fast path
#define SHIFT8  2.0794415416798357f   // log(8), fallback path
// ws float offsets: X[64][128] | Q[64][128] | scalars[4cg][2dir][3][32seg][16n]
#define WX 0
#define WQ 8192
#define WSC 16384
#define FAST_WS_BYTES 114688u                    // tier-2 (R9 gather engine)
#define EO2_OFF 131072u                          // eo fp16 tiles, 128KB-aligned
#define FAST2_WS_BYTES (EO2_OFF + 67108864u)     // tier-1 (prep + eo engine)

#define WAIT_VM(n)   asm volatile("s_waitcnt vmcnt(" #n ")" ::: "memory")

// inline-asm global load: program-order issue, counted vmcnt, can't be sunk
#define GL4(dst, addr, OFFSTR) \
    asm volatile("global_load_dwordx4 %0, %1, off offset:" OFFSTR \
                 : "=v"(dst) : "v"(addr))

__device__ __forceinline__ h2 pkrtz(float a, float b) {
    return __builtin_bit_cast(h2, __builtin_amdgcn_cvt_pkrtz(a, b));
}

// (a,b) <- ([a.lanes0-31 | b.lanes0-31], [a.lanes32-63 | b.lanes32-63])
__device__ __forceinline__ void swap32(uint32& a, uint32& b) {
#if __has_builtin(__builtin_amdgcn_permlane32_swap)
    u2v r = __builtin_amdgcn_permlane32_swap(a, b, false, false);
    a = r.x; b = r.y;
#else
    const uint32 pa = (uint32)__shfl_xor((int)a, 32);
    const uint32 pb = (uint32)__shfl_xor((int)b, 32);
    const bool hi = (threadIdx.x & 32) != 0;
    const uint32 na = hi ? pb : a;
    const uint32 nb = hi ? b : pa;
    a = na; b = nb;
#endif
}
// per 32-lane half: (a,b) <- ([a0-15|b0-15|a32-47|b32-47], [a16-31|b16-31|a48-63|b48-63])
__device__ __forceinline__ void swap16(uint32& a, uint32& b) {
#if __has_builtin(__builtin_amdgcn_permlane16_swap)
    u2v r = __builtin_amdgcn_permlane16_swap(a, b, false, false);
    a = r.x; b = r.y;
#else
    const uint32 sa = (uint32)__builtin_amdgcn_ds_swizzle((int)a, 0x401F);
    const uint32 sb = (uint32)__builtin_amdgcn_ds_swizzle((int)b, 0x401F);
    const bool m = (threadIdx.x & 16) != 0;
    const uint32 na = m ? sb : a;
    const uint32 nb = m ? b : sa;
    a = na; b = nb;
#endif
}

// pure-VALU wave max over lane bits 4 and 5
__device__ __forceinline__ float wavemax_hi(float M) {
    uint32 ma = __builtin_bit_cast(uint32, M), mb = ma;
    swap16(ma, mb);
    M = fmaxf(__builtin_bit_cast(float, ma), __builtin_bit_cast(float, mb));
    ma = __builtin_bit_cast(uint32, M); mb = ma;
    swap32(ma, mb);
    return fmaxf(__builtin_bit_cast(float, ma), __builtin_bit_cast(float, mb));
}

// pure-VALU wave sum over lane bits 4 and 5 (sums the 4 q-lanes of a chain)
__device__ __forceinline__ float wavesum_hi(float S) {
    uint32 a = __builtin_bit_cast(uint32, S), b = a;
    swap16(a, b);
    S = __builtin_bit_cast(float, a) + __builtin_bit_cast(float, b);
    a = __builtin_bit_cast(uint32, S); b = a;
    swap32(a, b);
    return __builtin_bit_cast(float, a) + __builtin_bit_cast(float, b);
}

// per-chain sum of the 128-state vector held in D (across mt, elems, q-lanes)
__device__ __forceinline__ float chain_sum(const f4 (&D)[8]) {
    f4 s4 = (D[0] + D[1]) + (D[2] + D[3]);
    s4 = s4 + ((D[4] + D[5]) + (D[6] + D[7]));
    float S = (s4.x + s4.y) + (s4.z + s4.w);
    return wavesum_hi(S);
}

// ============================ FAST PATH =====================================

#define TE(N) (FW ? (N) : (4095 - (N)))
#define WSEG 32      // warmup substeps (validated R8/R9)
#define LSEG 64      // main substeps per segment -> read multiplicity 1.5x
#define NSEG 32      // 2048 / LSEG

template <bool FW, int ST>
__device__ __forceinline__ void cstep(int v, int nv, bool head,
                                      f4 (&D)[8], const uint32* ep,
                                      const h8 (&Af)[8][4],
                                      float& Lacc, float& rs, float& saK)
{
    const f4 Z = {0.f, 0.f, 0.f, 0.f};

    if (ST == 0) {                       // apply pending renorm (fp32, exact)
        #pragma unroll
        for (int mt = 0; mt < 8; ++mt) D[mt] = D[mt] * rs;
        if (v == WSEG) {                 // segment boundary: end of warmup
            if (head) {                  // exact chain head: true init
                #pragma unroll
                for (int mt = 0; mt < 8; ++mt) D[mt] = (f4){1.f, 1.f, 1.f, 1.f};
            } else {
                saK = chain_sum(D);      // warm-start direction sum (per chain)
            }
            Lacc = 0.f;                  // discard warmup scale bookkeeping
        }
    }
    if (ST == 3) {
        if (v != nv - 1) {               // measure; pure VALU (permlane max)
            f4 m01 = __builtin_elementwise_max(D[0], D[1]);
            f4 m23 = __builtin_elementwise_max(D[2], D[3]);
            f4 m45 = __builtin_elementwise_max(D[4], D[5]);
            f4 m67 = __builtin_elementwise_max(D[6], D[7]);
            f4 ma = __builtin_elementwise_max(
                        __builtin_elementwise_max(m01, m23),
                        __builtin_elementwise_max(m45, m67));
            float M = fmaxf(fmaxf(ma.x, ma.y), fmaxf(ma.z, ma.w));
            M = wavemax_hi(M);
            Lacc += __logf(M);
            rs = __builtin_amdgcn_rcpf(M);
        }
    }

    // pack W = fp16(D) * eo  (register-resident)
    uint32 Wx[8], Wy[8];
    #pragma unroll
    for (int mt = 0; mt < 8; ++mt) {
        h2 w0 = pkrtz(D[mt].x, D[mt].y) * __builtin_bit_cast(h2, ep[2 * mt]);
        h2 w1 = pkrtz(D[mt].z, D[mt].w) * __builtin_bit_cast(h2, ep[2 * mt + 1]);
        Wx[mt] = __builtin_bit_cast(uint32, w0);
        Wy[mt] = __builtin_bit_cast(uint32, w1);
    }

    // cross-lane permute D-layout -> B-fragment layout (no LDS)
    h8 Bf[4];
    #pragma unroll
    for (int kc = 0; kc < 4; ++kc) {
        uint32 x0 = Wx[2 * kc], x1 = Wx[2 * kc + 1];
        uint32 y0 = Wy[2 * kc], y1 = Wy[2 * kc + 1];
        swap32(x0, x1); swap16(x0, x1);   // x0=d0, x1=d2
        swap32(y0, y1); swap16(y0, y1);   // y0=d1, y1=d3
        uint4 bv; bv.x = x0; bv.y = y0; bv.z = x1; bv.w = y1;
        Bf[kc] = __builtin_bit_cast(h8, bv);
    }

    // 32 MFMAs: 8 independent mt chains of depth 4
    #pragma unroll
    for (int mt = 0; mt < 8; ++mt) {
        f4 acc = Z;
        acc = __builtin_amdgcn_mfma_f32_16x16x32_f16(Af[mt][0], Bf[0], acc, 0, 0, 0);
        acc = __builtin_amdgcn_mfma_f32_16x16x32_f16(Af[mt][1], Bf[1], acc, 0, 0, 0);
        acc = __builtin_amdgcn_mfma_f32_16x16x32_f16(Af[mt][2], Bf[2], acc, 0, 0, 0);
        acc = __builtin_amdgcn_mfma_f32_16x16x32_f16(Af[mt][3], Bf[3], acc, 0, 0, 0);
        D[mt] = acc;
    }
}

// shared A-fragment setup
#define AF_SETUP()                                                            \
    h8 Af[8][4];                                                              \
    _Pragma("unroll")                                                         \
    for (int mt = 0; mt < 8; ++mt)                                            \
        _Pragma("unroll")                                                     \
        for (int kc = 0; kc < 4; ++kc) {                                      \
            h8 a;                                                             \
            _Pragma("unroll")                                                 \
            for (int j = 0; j < 8; ++j) {                                     \
                const int k = kc * 32 + q * 8 + j;                            \
                const int m = mt * 16 + n;                                    \
                a[j] = (half_t)__expf(FW ? trans[k * 128 + m]                 \
                                         : trans[m * 128 + k]);               \
            }                                                                 \
            Af[mt][kc] = a;                                                   \
        }

#define EPILOGUE(DD, LACC, SAK)                                               \
    const float swK = chain_sum(DD);                                          \
    if (last) {                                                               \
        float* Xo = ws + (FW ? WX : WQ) + ((cg * 16 + n) << 7);               \
        _Pragma("unroll")                                                     \
        for (int mt = 0; mt < 8; ++mt)                                        \
            *(f4*)&Xo[mt * 16 + q * 4] = DD[mt];                              \
    }                                                                         \
    float* sc = ws + WSC + (cg * 2 + (FW ? 0 : 1)) * 1536;                    \
    if (q == 0) {                                                             \
        sc[sg * 16 + n]        = LACC;                                        \
        sc[512 + sg * 16 + n]  = swK;                                         \
        sc[1024 + sg * 16 + n] = head ? 1.0f : SAK;                           \
    }

// ---------------- tier-1: eo_prep + contiguous-fp16 consumer ----------------

// eo16[cg][t][g 0..3][lane l]: fp16 exp(obs-SHIFT16) pairs in per-lane MFMA
// ep order; lane's 16 dwords per tile live as 4 contiguous 16B chunks
// (byte g*1024 + l*16). LDS-staged transpose (validated R2/R3).
__global__ __launch_bounds__(256)
void eo_prep(const float* __restrict__ obs, uint32* __restrict__ eo)
{
    __shared__ float sb[64 * 130];       // 64 rows (n,tl) x 128 floats, padded
    const int tid = threadIdx.x;
    const int cg = blockIdx.x >> 10;     // 4 chain-groups
    const int tb = blockIdx.x & 1023;    // 1024 blocks of 4 timesteps

    #pragma unroll
    for (int i = 0; i < 8; ++i) {        // load 64x128 floats, coalesced
        const int idx = i * 256 + tid;   // 2048 float4s
        const int row = idx >> 5, c4 = idx & 31;
        const int n = row >> 2, tl = row & 3;
        const float4 v = *(const float4*)
            &obs[((size_t)(cg * 16 + n) * 4096 + (tb * 4 + tl)) * 128 + c4 * 4];
        *(float4*)&sb[row * 130 + c4 * 4] = v;
    }
    __syncthreads();

    const int gg = tid >> 6;             // dword-group 0..3
    const int l  = tid & 63;             // output lane 0..63
    const int q = l >> 4, nn = l & 15;
    #pragma unroll
    for (int tl = 0; tl < 4; ++tl) {
        uint4 o;
        uint32* po = &o.x;
        #pragma unroll
        for (int j = 0; j < 4; ++j) {
            const int hd = gg * 4 + j;
            const int mt = hd >> 1, rr = (hd & 1) * 2;
            const int s = mt * 16 + q * 4 + rr;
            const float* p = &sb[(nn * 4 + tl) * 130 + s];
            po[j] = __builtin_bit_cast(uint32,
                      pkrtz(__expf(p[0] - SHIFT16), __expf(p[1] - SHIFT16)));
        }
        *(uint4*)&eo[((size_t)(cg * 4096 + tb * 4 + tl) << 10) + (gg << 8) + (l << 2)] = o;
    }
}

// Issue 4 contiguous 16B loads of this lane's ep-tile (timestep ip) into G[B].
#define ISSUE4(B, IPE) do {                                                   \
    int ip_ = (IPE);                                                          \
    ip_ = ip_ < 0 ? 0 : (ip_ > NITd - 1 ? NITd - 1 : ip_);                    \
    const u64 a_ = lbase + ((u64)TE(ip_) << 12);                              \
    GL4(G[B][0], a_, "0");    GL4(G[B][1], a_, "1024");                       \
    GL4(G[B][2], a_, "2048"); GL4(G[B][3], a_, "3072");                       \
} while (0)

// One substep: issue tile v+3 (depth-3, counted vmcnt), wait tile v
// (vmcnt(12) = 3 tiles x 4 loads in flight), compute. No exp/pack: eo is
// pre-packed ep dwords; G[B][0..3] ARE ep[0..15].
#define ESUBSTEP(U)  do {                                                     \
    const int v_ = tt * 8 + (U);                                              \
    if (v_ < nv) {                                                            \
        ISSUE4(((U) + 3) & 3, itb + v_ + 3);                                  \
        WAIT_VM(12);                     /* tile v landed in G[U&3] */        \
        __builtin_amdgcn_sched_barrier(0);                                    \
        cstep<FW, (U) & 3>(v_, nv, head, D, (const uint32*)&G[(U) & 3][0],    \
                           Af, Lacc, rs, saK);                                \
    } } while (0)

template <bool FW>
__device__ __forceinline__ void chain_eo(const uint32* __restrict__ eo,
                                         const float* __restrict__ trans,
                                         float* __restrict__ ws, int cg, int sg)
{
    const int l = threadIdx.x & 63;
    const int q = l >> 4, n = l & 15;
    const int NITd = FW ? 2048 : 2047;
    const int nv   = (!FW && sg == NSEG - 1) ? (WSEG + LSEG - 1) : (WSEG + LSEG);
    const bool head = (sg == 0);
    const bool last = (sg == NSEG - 1);
    const int itb = sg * LSEG - WSEG;    // global it = itb + v
    const u64 lbase = (u64)(const char*)eo + ((u64)cg << 24) + (u64)(l << 4);

    AF_SETUP();

    uint4 G[4][4];                        // 4-tile register ring (static idx)
    ISSUE4(0, itb + 0);                   // prologue: tiles 0,1,2 in flight
    ISSUE4(1, itb + 1);
    ISSUE4(2, itb + 2);

    f4 D[8];
    #pragma unroll
    for (int mt = 0; mt < 8; ++mt) D[mt] = (f4){1.f, 1.f, 1.f, 1.f};
    float Lacc = 0.f, rs = 1.f, saK = 1.f;

    #pragma unroll 1
    for (int tt = 0; tt < (WSEG + LSEG) / 8; ++tt) {
        ESUBSTEP(0); ESUBSTEP(1); ESUBSTEP(2); ESUBSTEP(3);
        ESUBSTEP(4); ESUBSTEP(5); ESUBSTEP(6); ESUBSTEP(7);
    }
    WAIT_VM(0);                           // drain leftover prefetches

    EPILOGUE(D, Lacc, saK);
}

__global__ __launch_bounds__(64, 1)
void crf_mfma_eo(const uint32* __restrict__ eo, const float* __restrict__ trans,
                 float* __restrict__ ws)
{
    const int bid = blockIdx.x;           // 256 blocks: dir*128 + cg*32 + sg
    const int r = bid & 127;
    const int cg = r >> 5, sg = r & 31;
    if (bid < 128) chain_eo<true >(eo, trans, ws, cg, sg);
    else           chain_eo<false>(eo, trans, ws, cg, sg);
}

// ---------------- tier-2: validated R9 fp32-gather engine -------------------

#define ISSUE8(B, IPE) do {                                                   \
    int ip_ = (IPE);                                                          \
    ip_ = ip_ < 0 ? 0 : (ip_ > NITd - 1 ? NITd - 1 : ip_);                    \
    const u64 a_ = lbase + ((u64)TE(ip_) << 9);                               \
    GL4(G[B][0], a_, "0");   GL4(G[B][1], a_, "64");                          \
    GL4(G[B][2], a_, "128"); GL4(G[B][3], a_, "192");                         \
    GL4(G[B][4], a_, "256"); GL4(G[B][5], a_, "320");                         \
    GL4(G[B][6], a_, "384"); GL4(G[B][7], a_, "448");                         \
} while (0)

#define SUBSTEP(U)  do {                                                      \
    const int v_ = tt * 8 + (U);                                              \
    if (v_ < nv) {                                                            \
        ISSUE8(((U) + 3) & 3, itb + v_ + 3);                                  \
        WAIT_VM(24);                     /* tile v landed in G[U&3] */        \
        __builtin_amdgcn_sched_barrier(0);                                    \
        uint32 ep[16];                                                        \
        _Pragma("unroll")                                                     \
        for (int mt = 0; mt < 8; ++mt) {                                      \
            const f4 ov = __builtin_bit_cast(f4, G[(U) & 3][mt]);             \
            ep[2 * mt] = __builtin_bit_cast(uint32,                           \
                pkrtz(__expf(ov.x - SHIFT16), __expf(ov.y - SHIFT16)));       \
            ep[2 * mt + 1] = __builtin_bit_cast(uint32,                       \
                pkrtz(__expf(ov.z - SHIFT16), __expf(ov.w - SHIFT16)));       \
        }                                                                     \
        cstep<FW, (U) & 3>(v_, nv, head, D, ep, Af, Lacc, rs, saK);           \
    } } while (0)

template <bool FW>
__device__ __forceinline__ void chain_g(const float* __restrict__ obs,
                                        const float* __restrict__ trans,
                                        float* __restrict__ ws, int cg, int sg)
{
    const int l = threadIdx.x & 63;
    const int q = l >> 4, n = l & 15;
    const int NITd = FW ? 2048 : 2047;
    const int nv   = (!FW && sg == NSEG - 1) ? (WSEG + LSEG - 1) : (WSEG + LSEG);
    const bool head = (sg == 0);
    const bool last = (sg == NSEG - 1);
    const int itb = sg * LSEG - WSEG;
    const u64 lbase = (u64)(const char*)obs
                    + ((u64)(cg * 16 + n) << 21) + (u64)(q << 4);

    AF_SETUP();

    uint4 G[4][8];
    ISSUE8(0, itb + 0);
    ISSUE8(1, itb + 1);
    ISSUE8(2, itb + 2);

    f4 D[8];
    #pragma unroll
    for (int mt = 0; mt < 8; ++mt) D[mt] = (f4){1.f, 1.f, 1.f, 1.f};
    float Lacc = 0.f, rs = 1.f, saK = 1.f;

    #pragma unroll 1
    for (int tt = 0; tt < (WSEG + LSEG) / 8; ++tt) {
        SUBSTEP(0); SUBSTEP(1); SUBSTEP(2); SUBSTEP(3);
        SUBSTEP(4); SUBSTEP(5); SUBSTEP(6); SUBSTEP(7);
    }
    WAIT_VM(0);

    EPILOGUE(D, Lacc, saK);
}

__global__ __launch_bounds__(64, 1)
void crf_mfma_g(const float* __restrict__ obs, const float* __restrict__ trans,
                float* __restrict__ ws)
{
    const int bid = blockIdx.x;           // 256 blocks
    const int g = bid & 7;                // dir*4 + cg (XCD-locality decode)
    const int sg = bid >> 3;
    const int cg = g & 3;
    if (g < 4) chain_g<true >(obs, trans, ws, cg, sg);
    else       chain_g<false>(obs, trans, ws, cg, sg);
}

// Z = sum_s X[s]*eo_2048[s]*Q[s]; out = -(log Z + corrections + 4096*SHIFT16)
// corrections: per dir: sum_s L_s + sum_{s>=1} [log sw_{s-1} - log sa_s].
// Lane l handles (dir = l>>5, segment = l&31); shuffle-reduced over 64 lanes.
__global__ __launch_bounds__(64)
void crf_comb(const float* __restrict__ obs, const float* __restrict__ ws,
              float* __restrict__ out)
{
    const int b = blockIdx.x, l = threadIdx.x;
    const int cg = b >> 4, n = b & 15;
    const int s0 = 2 * l;
    const float2 o = *(const float2*)&obs[((((size_t)b << 12) + 2048) << 7) + s0];
    const float e0 = __expf(o.x - SHIFT16), e1 = __expf(o.y - SHIFT16);
    float v = ws[WX + b * 128 + s0] * e0 * ws[WQ + b * 128 + s0]
            + ws[WX + b * 128 + s0 + 1] * e1 * ws[WQ + b * 128 + s0 + 1];

    const int dir = l >> 5, s = l & 31;   // per-lane segment partial
    const float* sc = ws + WSC + (cg * 2 + dir) * 1536;
    float corr = sc[s * 16 + n];
    if (s >= 1)
        corr += __logf(sc[512 + (s - 1) * 16 + n])
              - __logf(sc[1024 + s * 16 + n]);

    v += __shfl_xor(v, 1);  v += __shfl_xor(v, 2);  v += __shfl_xor(v, 4);
    v += __shfl_xor(v, 8);  v += __shfl_xor(v, 16); v += __shfl_xor(v, 32);
    corr += __shfl_xor(corr, 1);  corr += __shfl_xor(corr, 2);
    corr += __shfl_xor(corr, 4);  corr += __shfl_xor(corr, 8);
    corr += __shfl_xor(corr, 16); corr += __shfl_xor(corr, 32);
    if (l == 0)
        out[b] = -(__logf(v) + corr + 4096.0f * SHIFT16);
}

// ======================= FALLBACK (ws too small) ============================

typedef _Float16 h2f __attribute__((ext_vector_type(2)));
#define FTILE 16
#define FNTILE 128

#if __has_builtin(__builtin_amdgcn_fdot2)
#define FDOT2(p, e, acc) __builtin_amdgcn_fdot2((p), (e), (acc), false)
#else
#define FDOT2(p, e, acc) fmaf((float)(p).x, (float)(e).x, fmaf((float)(p).y, (float)(e).y, (acc)))
#endif

__device__ __forceinline__ h2f u2h(uint32 u) { return __builtin_bit_cast(h2f, u); }
__device__ __forceinline__ uint32 f2h(float f) {
    return (uint32)__builtin_bit_cast(unsigned short, (half_t)f);
}

#define FSTEP(N0, APPLY, MEAS)  do {                                                \
    const int row_ = fw ? ((N0) & (FTILE - 1)) : ((FTILE - 1) - ((N0) & (FTILE - 1))); \
    const float2 o2_ = *(const float2*)&obsL[(((N0) >> 4) & 1) * (FTILE * 128) + (row_ << 7) + (l << 1)]; \
    float e0_ = __expf(o2_.x - SHIFT8);                                             \
    float e1_ = __expf(o2_.y - SHIFT8);                                             \
    if (APPLY) { e0_ *= rsf; e1_ *= rsf; }                                          \
    float w0_, w1_;                                                                 \
    if (fw) { w0_ = pv0; w1_ = pv1; } else { w0_ = pv0 * e0_; w1_ = pv1 * e1_; }    \
    Pl[l] = (f2h(w1_) << 16) | f2h(w0_);                                            \
    float a0_=0.f,a1_=0.f,a2_=0.f,a3_=0.f,b0_=0.f,b1_=0.f,b2_=0.f,b3_=0.f;          \
    _Pragma("unroll")                                                               \
    for (int c_ = 0; c_ < 16; ++c_) {                                               \
        const uint4 q_ = ((const uint4*)Pl)[c_];                                    \
        const h2f p0_ = u2h(q_.x), p1_ = u2h(q_.y), p2_ = u2h(q_.z), p3_ = u2h(q_.w); \
        a0_ = FDOT2(p0_, eA[4*c_+0], a0_);                                          \
        a1_ = FDOT2(p1_, eA[4*c_+1], a1_);                                          \
        a2_ = FDOT2(p2_, eA[4*c_+2], a2_);                                          \
        a3_ = FDOT2(p3_, eA[4*c_+3], a3_);                                          \
        b0_ = FDOT2(p0_, eB[4*c_+0], b0_);                                          \
        b1_ = FDOT2(p1_, eB[4*c_+1], b1_);                                          \
        b2_ = FDOT2(p2_, eB[4*c_+2], b2_);                                          \
        b3_ = FDOT2(p3_, eB[4*c_+3], b3_);                                          \
    }                                                                               \
    const float s0_ = (a0_ + a1_) + (a2_ + a3_);                                    \
    const float s1_ = (b0_ + b1_) + (b2_ + b3_);                                    \
    if (fw) { pv0 = s0_ * e0_; pv1 = s1_ * e1_; } else { pv0 = s0_; pv1 = s1_; }    \
    if (MEAS) {                                                                     \
        float m_ = fmaxf(pv0, pv1);                                                 \
        m_ = fmaxf(m_, __shfl_xor(m_, 1));                                          \
        m_ = fmaxf(m_, __shfl_xor(m_, 2));                                          \
        m_ = fmaxf(m_, __shfl_xor(m_, 4));                                          \
        m_ = fmaxf(m_, __shfl_xor(m_, 8));                                          \
        m_ = fmaxf(m_, __shfl_xor(m_, 16));                                         \
        m_ = fmaxf(m_, __shfl_xor(m_, 32));                                         \
        rsf = __builtin_amdgcn_rcpf(m_);                                            \
        Lacc += __logf(m_);                                                         \
    }                                                                               \
} while (0)

#define FLOADR(TK) do {                                                             \
    const float4* g_ = (const float4*)(obsB + (size_t)(fw ? (TK) * (FTILE * 128)    \
                                      : (4096 - FTILE * ((TK) + 1)) * 128));        \
    r0 = g_[l];       r1 = g_[l + 64];  r2 = g_[l + 128]; r3 = g_[l + 192];         \
    r4 = g_[l + 256]; r5 = g_[l + 320]; r6 = g_[l + 384]; r7 = g_[l + 448];         \
} while (0)

#define FSTORER(TK) do {                                                            \
    float4* s_ = (float4*)&obsL[((TK) & 1) * (FTILE * 128)];                        \
    s_[l] = r0;       s_[l + 64] = r1;  s_[l + 128] = r2; s_[l + 192] = r3;         \
    s_[l + 256] = r4; s_[l + 320] = r5; s_[l + 384] = r6; s_[l + 448] = r7;         \
} while (0)

__global__ __launch_bounds__(64, 1)
void crf_half_fb(const float* __restrict__ obs, const float* __restrict__ trans,
                 float* __restrict__ ws)
{
    __shared__ __align__(16) uint32 Pl[64];
    __shared__ __align__(16) float obsL[2 * FTILE * 128];

    const int l  = threadIdx.x;
    const bool fw = blockIdx.x < 64;
    const int b  = fw ? blockIdx.x : blockIdx.x - 64;
    const float* obsB = obs + (size_t)b * 4096 * 128;

    h2f eA[64], eB[64];
    if (fw) {
        const int c0 = 2 * l;
        #pragma unroll
        for (int k = 0; k < 64; ++k) {
            h2f ta, tb;
            ta.x = (half_t)__expf(trans[(2*k    ) * 128 + c0]);
            ta.y = (half_t)__expf(trans[(2*k + 1) * 128 + c0]);
            tb.x = (half_t)__expf(trans[(2*k    ) * 128 + c0 + 1]);
            tb.y = (half_t)__expf(trans[(2*k + 1) * 128 + c0 + 1]);
            eA[k] = ta; eB[k] = tb;
        }
    } else {
        const int ro0 = (2 * l) * 128, ro1 = (2 * l + 1) * 128;
        #pragma unroll
        for (int k = 0; k < 64; ++k) {
            h2f ta, tb;
            ta.x = (half_t)__expf(trans[ro0 + 2*k]);
            ta.y = (half_t)__expf(trans[ro0 + 2*k + 1]);
            tb.x = (half_t)__expf(trans[ro1 + 2*k]);
            tb.y = (half_t)__expf(trans[ro1 + 2*k + 1]);
            eA[k] = ta; eB[k] = tb;
        }
    }

    float4 r0, r1, r2, r3, r4, r5, r6, r7;
    FLOADR(0);
    FSTORER(0);
    FLOADR(1);

    float rsf = 1.f, Lacc = 0.f, pv0, pv1;

    if (fw) {
        const float2 o2 = *(const float2*)&obsL[l << 1];
        pv0 = __expf(o2.x - SHIFT8);
        pv1 = __expf(o2.y - SHIFT8);
    } else {
        pv0 = 1.f; pv1 = 1.f;
        FSTEP(0, false, false);
    }

    for (int tile = 0; tile < FNTILE; ++tile) {
        if (tile > 0) {
            FSTORER(tile);
            if (tile < FNTILE - 1) FLOADR(tile + 1);
        }
        const int nb = tile << 4;
        #pragma unroll 1
        for (int g = 0; g < 4; ++g) {
            const int n0 = nb + (g << 2);
            if (n0 > 0) FSTEP(n0, true, false);
            FSTEP(n0 + 1, false, false);
            FSTEP(n0 + 2, false, false);
            if (n0 + 3 != 2047) FSTEP(n0 + 3, false, true);
            else                FSTEP(n0 + 3, false, false);
        }
    }

    if (fw) {
        ws[b * 128 + 2*l]     = pv0;
        ws[b * 128 + 2*l + 1] = pv1;
        if (l == 0) ws[16384 + b] = Lacc;
    } else {
        ws[8192 + b * 128 + 2*l]     = pv0;
        ws[8192 + b * 128 + 2*l + 1] = pv1;
        if (l == 0) ws[16448 + b] = Lacc;
    }
}

__global__ __launch_bounds__(64)
void crf_comb_fb(const float* __restrict__ ws, float* __restrict__ out)
{
    const int b = blockIdx.x, l = threadIdx.x;
    float s = ws[b * 128 + 2*l] * ws[8192 + b * 128 + 2*l]
            + ws[b * 128 + 2*l + 1] * ws[8192 + b * 128 + 2*l + 1];
    s += __shfl_xor(s, 1);  s += __shfl_xor(s, 2);  s += __shfl_xor(s, 4);
    s += __shfl_xor(s, 8);  s += __shfl_xor(s, 16); s += __shfl_xor(s, 32);
    if (l == 0)
        out[b] = -(__logf(s) + ws[16384 + b] + ws[16448 + b] + 4096.0f * SHIFT8);
}

// ============================================================================

extern "C" void kernel_launch(void* const* d_in, const int* in_sizes, int n_in,
                              void* d_out, int out_size, void* d_ws, size_t ws_size,
                              hipStream_t stream) {
    (void)in_sizes; (void)n_in; (void)out_size;
    const float* obs   = (const float*)d_in[0];   // [64, 4096, 128] fp32
    const float* trans = (const float*)d_in[1];   // [128, 128] fp32
    float* out = (float*)d_out;                   // [64] fp32
    float* ws  = (float*)d_ws;

    if (ws_size >= (size_t)FAST2_WS_BYTES) {
        uint32* eo = (uint32*)((char*)d_ws + EO2_OFF);
        hipLaunchKernelGGL(eo_prep,     dim3(4096), dim3(256), 0, stream, obs, eo);
        hipLaunchKernelGGL(crf_mfma_eo, dim3(256),  dim3(64),  0, stream, eo, trans, ws);
        hipLaunchKernelGGL(crf_comb,    dim3(64),   dim3(64),  0, stream, obs, ws, out);
    } else if (ws_size >= (size_t)FAST_WS_BYTES) {
        hipLaunchKernelGGL(crf_mfma_g, dim3(256), dim3(64), 0, stream, obs, trans, ws);
        hipLaunchKernelGGL(crf_comb,   dim3(64),  dim3(64), 0, stream, obs, ws, out);
    } else {
        hipLaunchKernelGGL(crf_half_fb, dim3(128), dim3(64), 0, stream, obs, trans, ws);
        hipLaunchKernelGGL(crf_comb_fb, dim3(64),  dim3(64), 0, stream, ws, out);
    }
}